// Round 1
// baseline (1426.603 us; speedup 1.0000x reference)
//
#include <hip/hip_runtime.h>
#include <math.h>

#define R_ 4
#define TOTAL_ 32768
#define NNODE_ 1024
#define B_ 32
#define DH_ 256
#define C_ 8
#define H_ 8
#define NCLS_ 10
#define E_ 262144

// ---------------- graph prep ----------------

__global__ void zero_i32(int* p, int n) {
  int i = blockIdx.x * blockDim.x + threadIdx.x;
  if (i < n) p[i] = 0;
}

__global__ void count_deg(const int* __restrict__ src, const int* __restrict__ dst,
                          int* __restrict__ cnt_out, int* __restrict__ cnt_in) {
  int i = blockIdx.x * blockDim.x + threadIdx.x;
  if (i < R_ * E_) {
    int r = i / E_;
    atomicAdd(&cnt_out[r * TOTAL_ + src[i]], 1);
    atomicAdd(&cnt_in[r * TOTAL_ + dst[i]], 1);
  }
}

__global__ void deg_rsqrt(const int* __restrict__ cnt_out, const int* __restrict__ cnt_in,
                          float* __restrict__ rs_out, float* __restrict__ rs_in) {
  int i = blockIdx.x * blockDim.x + threadIdx.x;
  if (i < R_ * TOTAL_) {
    rs_out[i] = rsqrtf((float)(cnt_out[i] + 1));  // +1 self loop; always >=1
    rs_in[i]  = rsqrtf((float)(cnt_in[i] + 1));
  }
}

// one block per relation: exclusive scan of in-degree counts -> CSR offsets
__global__ __launch_bounds__(1024) void scan_counts(const int* __restrict__ cnt_in,
                                                    int* __restrict__ off,
                                                    int* __restrict__ pos) {
  int r = blockIdx.x;
  const int* c = cnt_in + r * TOTAL_;
  int* o = off + r * (TOTAL_ + 1);
  __shared__ int part[1024];
  int t = threadIdx.x;
  int base = t * 32;
  int loc[32];
  int s = 0;
#pragma unroll
  for (int j = 0; j < 32; j++) { loc[j] = c[base + j]; s += loc[j]; }
  part[t] = s;
  __syncthreads();
  for (int d = 1; d < 1024; d <<= 1) {
    int v = (t >= d) ? part[t - d] : 0;
    __syncthreads();
    part[t] += v;
    __syncthreads();
  }
  int run = (t == 0) ? 0 : part[t - 1];
#pragma unroll
  for (int j = 0; j < 32; j++) {
    o[base + j] = run;
    pos[r * TOTAL_ + base + j] = run;
    run += loc[j];
  }
  if (t == 1023) o[TOTAL_] = run;
}

__global__ void build_csr(const int* __restrict__ src, const int* __restrict__ dst,
                          int* __restrict__ pos, int* __restrict__ csr_src) {
  int i = blockIdx.x * blockDim.x + threadIdx.x;
  if (i < R_ * E_) {
    int r = i / E_;
    int slot = atomicAdd(&pos[r * TOTAL_ + dst[i]], 1);
    csr_src[(size_t)r * E_ + slot] = src[i];
  }
}

// ---------------- graph conv ----------------

// one block (256 threads) per destination node; gather-only, no atomics
__global__ __launch_bounds__(256) void aggregate(const float* __restrict__ x,
                                                 const int* __restrict__ csr_off,
                                                 const int* __restrict__ csr_src,
                                                 const float* __restrict__ rs_out,
                                                 const float* __restrict__ rs_in,
                                                 float* __restrict__ agg, int r) {
  int v = blockIdx.x;
  int d = threadIdx.x;
  const int* offr = csr_off + r * (TOTAL_ + 1);
  const int* srcs = csr_src + (size_t)r * E_;
  const float* rso = rs_out + r * TOTAL_;
  float acc = x[(size_t)v * DH_ + d] * rso[v];  // self loop
  int e0 = offr[v], e1 = offr[v + 1];
  for (int e = e0; e < e1; ++e) {
    int s = srcs[e];
    acc += x[(size_t)s * DH_ + d] * rso[s];
  }
  agg[(size_t)v * DH_ + d] = acc * rs_in[r * TOTAL_ + v];
}

__global__ void init_bias(const float* __restrict__ b, float* __restrict__ out) {
  int i = blockIdx.x * blockDim.x + threadIdx.x;  // over TOTAL_*DH_
  int d = i & (DH_ - 1);
  out[i] = b[d] + b[DH_ + d] + b[2 * DH_ + d] + b[3 * DH_ + d];
}

__global__ void relu_k(float* __restrict__ x, int n) {
  int i = blockIdx.x * blockDim.x + threadIdx.x;
  if (i < n) x[i] = fmaxf(x[i], 0.f);
}

// C[M,256] += A[M,256] @ W[256,256]; 64x64 tile, BK=16, 4x4 per thread
__global__ __launch_bounds__(256) void gemm_acc256(const float* __restrict__ A,
                                                   const float* __restrict__ W,
                                                   float* __restrict__ C) {
  __shared__ float As[16][68];
  __shared__ float Bs[16][64];
  int t = threadIdx.x;
  int row0 = blockIdx.x * 64, col0 = blockIdx.y * 64;
  int tx = t & 15, ty = t >> 4;
  float acc[4][4] = {{0.f}};
  int am = t >> 2, ak = (t & 3) * 4;
  int bk = t >> 4, bn = (t & 15) * 4;
  for (int k0 = 0; k0 < 256; k0 += 16) {
    float4 av = *(const float4*)&A[(size_t)(row0 + am) * 256 + k0 + ak];
    As[ak + 0][am] = av.x; As[ak + 1][am] = av.y;
    As[ak + 2][am] = av.z; As[ak + 3][am] = av.w;
    *(float4*)&Bs[bk][bn] = *(const float4*)&W[(size_t)(k0 + bk) * 256 + col0 + bn];
    __syncthreads();
#pragma unroll
    for (int k = 0; k < 16; k++) {
      float4 a = *(const float4*)&As[k][ty * 4];
      float4 b = *(const float4*)&Bs[k][tx * 4];
      acc[0][0] += a.x * b.x; acc[0][1] += a.x * b.y; acc[0][2] += a.x * b.z; acc[0][3] += a.x * b.w;
      acc[1][0] += a.y * b.x; acc[1][1] += a.y * b.y; acc[1][2] += a.y * b.z; acc[1][3] += a.y * b.w;
      acc[2][0] += a.z * b.x; acc[2][1] += a.z * b.y; acc[2][2] += a.z * b.z; acc[2][3] += a.z * b.w;
      acc[3][0] += a.w * b.x; acc[3][1] += a.w * b.y; acc[3][2] += a.w * b.z; acc[3][3] += a.w * b.w;
    }
    __syncthreads();
  }
#pragma unroll
  for (int i = 0; i < 4; i++)
#pragma unroll
    for (int j = 0; j < 4; j++)
      C[(size_t)(row0 + ty * 4 + i) * 256 + col0 + tx * 4 + j] += acc[i][j];
}

// ---------------- pooling / attention / head ----------------

__global__ void cluster_count(const int* __restrict__ node_label, int* __restrict__ ccnt) {
  __shared__ int cnt[C_];
  if (threadIdx.x < C_) cnt[threadIdx.x] = 0;
  __syncthreads();
  for (int n = threadIdx.x; n < NNODE_; n += blockDim.x) atomicAdd(&cnt[node_label[n]], 1);
  __syncthreads();
  if (threadIdx.x < C_) ccnt[threadIdx.x] = cnt[threadIdx.x];
}

// one block per graph b: per-cluster masked means + overall node mean
__global__ __launch_bounds__(256) void pool_k(const float* __restrict__ h2,
                                              const int* __restrict__ node_label,
                                              const int* __restrict__ feat_label,
                                              const int* __restrict__ ccnt,
                                              float* __restrict__ poolv,
                                              float* __restrict__ hg_raw) {
  int b = blockIdx.x, d = threadIdx.x;
  __shared__ int slab[NNODE_];
  for (int n = threadIdx.x; n < NNODE_; n += 256) slab[n] = node_label[n];
  __syncthreads();
  float a[C_] = {0.f};
  float at = 0.f;
  const float* base = h2 + (size_t)b * NNODE_ * DH_ + d;
  for (int n = 0; n < NNODE_; n++) {
    float x = base[(size_t)n * DH_];
    int lab = slab[n];
    at += x;
#pragma unroll
    for (int k = 0; k < C_; k++) a[k] += (lab == k) ? x : 0.f;
  }
  int fl = feat_label[d];
#pragma unroll
  for (int k = 0; k < C_; k++) {
    float cntf = fmaxf((float)ccnt[k], 1.f);
    float v = (fl == k) ? (a[k] / cntf) : 0.f;
    poolv[((size_t)k * B_ + b) * DH_ + d] = v;
  }
  hg_raw[(size_t)b * DH_ + d] = at * (1.f / NNODE_);
}

// pooled[key] @ Wr[key]^T + br[key] -> emb_in[b][key][:]
__global__ __launch_bounds__(256) void resize_k(const float* __restrict__ poolv,
                                                const float* __restrict__ Wr,
                                                const float* __restrict__ br,
                                                float* __restrict__ emb_in) {
  int blk = blockIdx.x;
  int key = blk / B_, b = blk % B_;
  int j = threadIdx.x;
  __shared__ float v[DH_];
  v[j] = poolv[((size_t)key * B_ + b) * DH_ + j];
  __syncthreads();
  const float* wrow = Wr + ((size_t)key * DH_ + j) * DH_;
  float s = 0.f;
  for (int d = 0; d < DH_; d++) s += v[d] * wrow[d];
  emb_in[((size_t)b * C_ + key) * DH_ + j] = s + br[key * DH_ + j];
}

__global__ __launch_bounds__(256) void qkv_k(const float* __restrict__ emb_in,
                                             const float* __restrict__ Wq,
                                             const float* __restrict__ Wk,
                                             const float* __restrict__ Wv,
                                             float* __restrict__ q, float* __restrict__ k,
                                             float* __restrict__ v) {
  int b = blockIdx.x, d = threadIdx.x;
  __shared__ float x[C_][DH_];
  for (int c = 0; c < C_; c++) x[c][d] = emb_in[((size_t)b * C_ + c) * DH_ + d];
  __syncthreads();
  for (int c = 0; c < C_; c++) {
    float sq = 0.f, sk = 0.f, sv = 0.f;
    for (int kk = 0; kk < DH_; kk++) {
      float xv = x[c][kk];
      sq += xv * Wq[kk * DH_ + d];
      sk += xv * Wk[kk * DH_ + d];
      sv += xv * Wv[kk * DH_ + d];
    }
    q[((size_t)b * C_ + c) * DH_ + d] = sq;
    k[((size_t)b * C_ + c) * DH_ + d] = sk;
    v[((size_t)b * C_ + c) * DH_ + d] = sv;
  }
}

__global__ __launch_bounds__(256) void attn_k(const float* __restrict__ q,
                                              const float* __restrict__ k,
                                              const float* __restrict__ v,
                                              const float* __restrict__ emb_in,
                                              const float* __restrict__ lin_w,
                                              const float* __restrict__ lin_b,
                                              float* __restrict__ ge) {
  int b = blockIdx.x, t = threadIdx.x;
  __shared__ float qs[C_][DH_], ks[C_][DH_], vs[C_][DH_], os[C_][DH_];
  __shared__ float sc[H_][C_][C_];
  for (int c = 0; c < C_; c++) {
    qs[c][t] = q[((size_t)b * C_ + c) * DH_ + t];
    ks[c][t] = k[((size_t)b * C_ + c) * DH_ + t];
    vs[c][t] = v[((size_t)b * C_ + c) * DH_ + t];
  }
  __syncthreads();
  for (int idx = t; idx < H_ * C_ * C_; idx += 256) {
    int hh = idx / (C_ * C_);
    int qc = (idx / C_) % C_;
    int kc = idx % C_;
    float s = 0.f;
    for (int dd = 0; dd < 32; dd++) s += qs[qc][hh * 32 + dd] * ks[kc][hh * 32 + dd];
    sc[hh][qc][kc] = s * 0.35355339059327373f;  // 1/sqrt(C)
  }
  __syncthreads();
  if (t < H_ * C_) {
    int hh = t / C_, qc = t % C_;
    float m = -1e30f;
    for (int kc = 0; kc < C_; kc++) m = fmaxf(m, sc[hh][qc][kc]);
    float sum = 0.f;
    for (int kc = 0; kc < C_; kc++) { float e = expf(sc[hh][qc][kc] - m); sc[hh][qc][kc] = e; sum += e; }
    float inv = 1.f / sum;
    for (int kc = 0; kc < C_; kc++) sc[hh][qc][kc] *= inv;
  }
  __syncthreads();
  int hh = t >> 5;
  for (int c = 0; c < C_; c++) {
    float s = 0.f;
#pragma unroll
    for (int kc = 0; kc < C_; kc++) s += sc[hh][c][kc] * vs[kc][t];
    os[c][t] = s;
  }
  __syncthreads();
  const float* wrow = lin_w + (size_t)t * DH_;
  float s[C_] = {0.f};
  for (int d2 = 0; d2 < DH_; d2++) {
    float w = wrow[d2];
#pragma unroll
    for (int c = 0; c < C_; c++) s[c] += os[c][d2] * w;
  }
  float lbv = lin_b[t];
  float macc = 0.f;
#pragma unroll
  for (int c = 0; c < C_; c++) {
    float ff = fmaxf(s[c] + lbv, 0.f) + os[c][t];
    macc += ff + emb_in[((size_t)b * C_ + c) * DH_ + t];
  }
  ge[(size_t)b * DH_ + t] = macc * (1.f / C_);
}

__global__ void recon_k(const float* __restrict__ ge, const float* __restrict__ hg_raw,
                        float* __restrict__ out) {
  __shared__ float part[256];
  int t = threadIdx.x;
  float s = 0.f;
  for (int i = t; i < B_ * DH_; i += 256) {
    float d = ge[i] - hg_raw[i] + 1e-6f;
    s += d * d;
  }
  part[t] = s;
  __syncthreads();
  for (int sdl = 128; sdl > 0; sdl >>= 1) {
    if (t < sdl) part[t] += part[t + sdl];
    __syncthreads();
  }
  if (t == 0) out[B_ * NCLS_] = sqrtf(part[0]);
}

__global__ void bn_k(const float* __restrict__ ge, const float* __restrict__ g,
                     const float* __restrict__ be, float* __restrict__ hgn) {
  int d = threadIdx.x;
  float mu = 0.f;
  for (int b = 0; b < B_; b++) mu += ge[b * DH_ + d];
  mu *= (1.f / B_);
  float var = 0.f;
  for (int b = 0; b < B_; b++) { float x = ge[b * DH_ + d] - mu; var += x * x; }
  var *= (1.f / B_);
  float is = rsqrtf(var + 1e-5f);
  float gm = g[d], bt = be[d];
  for (int b = 0; b < B_; b++) hgn[b * DH_ + d] = (ge[b * DH_ + d] - mu) * is * gm + bt;
}

__global__ void logits_k(const float* __restrict__ hgn, const float* __restrict__ cw,
                         const float* __restrict__ cb, float* __restrict__ out) {
  int t = threadIdx.x;
  if (t < B_ * NCLS_) {
    int b = t / NCLS_, j = t % NCLS_;
    float s = cb[j];
    for (int d = 0; d < DH_; d++) s += hgn[b * DH_ + d] * cw[j * DH_ + d];
    out[t] = s;
  }
}

// ---------------- launch ----------------

extern "C" void kernel_launch(void* const* d_in, const int* in_sizes, int n_in,
                              void* d_out, int out_size, void* d_ws, size_t ws_size,
                              hipStream_t stream) {
  const float* h   = (const float*)d_in[0];
  const int* src   = (const int*)d_in[1];
  const int* dst   = (const int*)d_in[2];
  const int* nlab  = (const int*)d_in[3];
  const int* flab  = (const int*)d_in[4];
  const float* W1  = (const float*)d_in[5];
  const float* b1  = (const float*)d_in[6];
  const float* W2  = (const float*)d_in[7];
  const float* b2  = (const float*)d_in[8];
  const float* Wr  = (const float*)d_in[9];
  const float* br  = (const float*)d_in[10];
  const float* Wq  = (const float*)d_in[11];
  const float* Wk  = (const float*)d_in[12];
  const float* Wv  = (const float*)d_in[13];
  const float* lw  = (const float*)d_in[14];
  const float* lb  = (const float*)d_in[15];
  const float* bng = (const float*)d_in[16];
  const float* bnb = (const float*)d_in[17];
  const float* cw  = (const float*)d_in[18];
  const float* cb  = (const float*)d_in[19];
  float* out = (float*)d_out;

  char* p = (char*)d_ws;
  auto alloc = [&](size_t bytes) -> void* {
    void* q = (void*)p;
    p += (bytes + 255) & ~(size_t)255;
    return q;
  };
  float* h1     = (float*)alloc((size_t)TOTAL_ * DH_ * 4);
  float* h2     = (float*)alloc((size_t)TOTAL_ * DH_ * 4);
  float* agg    = (float*)alloc((size_t)TOTAL_ * DH_ * 4);
  int* cnt      = (int*)alloc((size_t)2 * R_ * TOTAL_ * 4);
  float* rs_out = (float*)alloc((size_t)R_ * TOTAL_ * 4);
  float* rs_in  = (float*)alloc((size_t)R_ * TOTAL_ * 4);
  int* csr_off  = (int*)alloc((size_t)R_ * (TOTAL_ + 1) * 4);
  int* csr_pos  = (int*)alloc((size_t)R_ * TOTAL_ * 4);
  int* csr_src  = (int*)alloc((size_t)R_ * E_ * 4);
  int* ccnt     = (int*)alloc(64);
  float* poolv  = (float*)alloc((size_t)C_ * B_ * DH_ * 4);
  float* hg_raw = (float*)alloc((size_t)B_ * DH_ * 4);
  float* emb_in = (float*)alloc((size_t)B_ * C_ * DH_ * 4);
  float* qb     = (float*)alloc((size_t)B_ * C_ * DH_ * 4);
  float* kb     = (float*)alloc((size_t)B_ * C_ * DH_ * 4);
  float* vb     = (float*)alloc((size_t)B_ * C_ * DH_ * 4);
  float* ge     = (float*)alloc((size_t)B_ * DH_ * 4);
  float* hgn    = (float*)alloc((size_t)B_ * DH_ * 4);

  int* cnt_out = cnt;
  int* cnt_in  = cnt + R_ * TOTAL_;

  zero_i32<<<(2 * R_ * TOTAL_ + 255) / 256, 256, 0, stream>>>(cnt, 2 * R_ * TOTAL_);
  count_deg<<<(R_ * E_ + 255) / 256, 256, 0, stream>>>(src, dst, cnt_out, cnt_in);
  deg_rsqrt<<<(R_ * TOTAL_ + 255) / 256, 256, 0, stream>>>(cnt_out, cnt_in, rs_out, rs_in);
  scan_counts<<<R_, 1024, 0, stream>>>(cnt_in, csr_off, csr_pos);
  build_csr<<<(R_ * E_ + 255) / 256, 256, 0, stream>>>(src, dst, csr_pos, csr_src);

  // layer 1
  init_bias<<<TOTAL_ * DH_ / 256, 256, 0, stream>>>(b1, h1);
  for (int r = 0; r < R_; r++) {
    aggregate<<<TOTAL_, 256, 0, stream>>>(h, csr_off, csr_src, rs_out, rs_in, agg, r);
    gemm_acc256<<<dim3(TOTAL_ / 64, 4), 256, 0, stream>>>(agg, W1 + (size_t)r * DH_ * DH_, h1);
  }
  relu_k<<<TOTAL_ * DH_ / 256, 256, 0, stream>>>(h1, TOTAL_ * DH_);

  // layer 2
  init_bias<<<TOTAL_ * DH_ / 256, 256, 0, stream>>>(b2, h2);
  for (int r = 0; r < R_; r++) {
    aggregate<<<TOTAL_, 256, 0, stream>>>(h1, csr_off, csr_src, rs_out, rs_in, agg, r);
    gemm_acc256<<<dim3(TOTAL_ / 64, 4), 256, 0, stream>>>(agg, W2 + (size_t)r * DH_ * DH_, h2);
  }

  // pooling + attention + head
  cluster_count<<<1, 256, 0, stream>>>(nlab, ccnt);
  pool_k<<<B_, 256, 0, stream>>>(h2, nlab, flab, ccnt, poolv, hg_raw);
  resize_k<<<C_ * B_, 256, 0, stream>>>(poolv, Wr, br, emb_in);
  qkv_k<<<B_, 256, 0, stream>>>(emb_in, Wq, Wk, Wv, qb, kb, vb);
  attn_k<<<B_, 256, 0, stream>>>(qb, kb, vb, emb_in, lw, lb, ge);
  recon_k<<<1, 256, 0, stream>>>(ge, hg_raw, out);
  bn_k<<<1, 256, 0, stream>>>(ge, bng, bnb, hgn);
  logits_k<<<1, 320, 0, stream>>>(hgn, cw, cb, out);
}

// Round 2
// 562.699 us; speedup vs baseline: 2.5353x; 2.5353x over previous
//
#include <hip/hip_runtime.h>
#include <math.h>

#define R_ 4
#define TOTAL_ 32768
#define NNODE_ 1024
#define B_ 32
#define DH_ 256
#define C_ 8
#define H_ 8
#define NCLS_ 10
#define E_ 262144

typedef __attribute__((ext_vector_type(8))) short short8v;
typedef __attribute__((ext_vector_type(8))) unsigned short u16x8;
typedef __attribute__((ext_vector_type(4))) unsigned short u16x4;
typedef __attribute__((ext_vector_type(4))) float f32x4;

__device__ inline unsigned short f2bf(float f) {
  unsigned int u = __builtin_bit_cast(unsigned int, f);
  u += 0x7FFF + ((u >> 16) & 1);
  return (unsigned short)(u >> 16);
}
__device__ inline float bf2f(unsigned short s) {
  return __builtin_bit_cast(float, (unsigned int)s << 16);
}

// ---------------- graph prep ----------------

__global__ void zero_i32(int* p, int n) {
  int i = blockIdx.x * blockDim.x + threadIdx.x;
  if (i < n) p[i] = 0;
}

__global__ void count_deg(const int* __restrict__ src, const int* __restrict__ dst,
                          int* __restrict__ cnt_out, int* __restrict__ cnt_in) {
  int i = blockIdx.x * blockDim.x + threadIdx.x;
  if (i < R_ * E_) {
    int r = i / E_;
    atomicAdd(&cnt_out[r * TOTAL_ + src[i]], 1);
    atomicAdd(&cnt_in[r * TOTAL_ + dst[i]], 1);
  }
}

__global__ void deg_rsqrt(const int* __restrict__ cnt_out, const int* __restrict__ cnt_in,
                          float* __restrict__ rs_out, float* __restrict__ rs_in) {
  int i = blockIdx.x * blockDim.x + threadIdx.x;
  if (i < R_ * TOTAL_) {
    rs_out[i] = rsqrtf((float)(cnt_out[i] + 1));
    rs_in[i]  = rsqrtf((float)(cnt_in[i] + 1));
  }
}

__global__ __launch_bounds__(1024) void scan_counts(const int* __restrict__ cnt_in,
                                                    int* __restrict__ off,
                                                    int* __restrict__ pos) {
  int r = blockIdx.x;
  const int* c = cnt_in + r * TOTAL_;
  int* o = off + r * (TOTAL_ + 1);
  __shared__ int part[1024];
  int t = threadIdx.x;
  int base = t * 32;
  int loc[32];
  int s = 0;
#pragma unroll
  for (int j = 0; j < 32; j++) { loc[j] = c[base + j]; s += loc[j]; }
  part[t] = s;
  __syncthreads();
  for (int d = 1; d < 1024; d <<= 1) {
    int v = (t >= d) ? part[t - d] : 0;
    __syncthreads();
    part[t] += v;
    __syncthreads();
  }
  int run = (t == 0) ? 0 : part[t - 1];
#pragma unroll
  for (int j = 0; j < 32; j++) {
    o[base + j] = run;
    pos[r * TOTAL_ + base + j] = run;
    run += loc[j];
  }
  if (t == 1023) o[TOTAL_] = run;
}

__global__ void build_csr(const int* __restrict__ src, const int* __restrict__ dst,
                          int* __restrict__ pos, int* __restrict__ csr_src) {
  int i = blockIdx.x * blockDim.x + threadIdx.x;
  if (i < R_ * E_) {
    int r = i / E_;
    int slot = atomicAdd(&pos[r * TOTAL_ + dst[i]], 1);
    csr_src[(size_t)r * E_ + slot] = src[i];
  }
}

// ---------------- conversions ----------------

// f32 [TOTAL,256] -> bf16, 4 elems/thread
__global__ void hconv(const float* __restrict__ x, unsigned short* __restrict__ xb) {
  int i = blockIdx.x * blockDim.x + threadIdx.x;
  float4 v = *(const float4*)&x[(size_t)i * 4];
  u16x4 o;
  o[0] = f2bf(v.x); o[1] = f2bf(v.y); o[2] = f2bf(v.z); o[3] = f2bf(v.w);
  *(u16x4*)&xb[(size_t)i * 4] = o;
}

// stacked W [1024,256] f32 -> Wt [256,1024] bf16
__global__ void wconv(const float* __restrict__ W, unsigned short* __restrict__ Wt) {
  int i = blockIdx.x * blockDim.x + threadIdx.x;  // 1024*256
  int k = i >> 8, c = i & 255;
  Wt[(size_t)c * 1024 + k] = f2bf(W[i]);
}

__global__ void bias_sum(const float* __restrict__ b, float* __restrict__ bs) {
  int d = threadIdx.x;
  bs[d] = b[d] + b[DH_ + d] + b[2 * DH_ + d] + b[3 * DH_ + d];
}

// ---------------- aggregation (bf16 gather) ----------------
// grid (TOTAL/8, R); 32 lanes per node, 8 bf16 per lane
__global__ __launch_bounds__(256) void aggregate_b(
    const unsigned short* __restrict__ xb, const int* __restrict__ csr_off,
    const int* __restrict__ csr_src, const float* __restrict__ rs_out,
    const float* __restrict__ rs_in, unsigned short* __restrict__ aggB) {
  int r = blockIdx.y;
  int node = blockIdx.x * 8 + (threadIdx.x >> 5);
  int c0 = (threadIdx.x & 31) * 8;
  const int* offr = csr_off + r * (TOTAL_ + 1);
  const int* srcs = csr_src + (size_t)r * E_;
  const float* rso = rs_out + r * TOTAL_;
  float acc[8];
  {
    u16x8 v = *(const u16x8*)&xb[(size_t)node * DH_ + c0];
    float w = rso[node];
#pragma unroll
    for (int j = 0; j < 8; j++) acc[j] = bf2f(v[j]) * w;
  }
  int e0 = offr[node], e1 = offr[node + 1];
  for (int e = e0; e < e1; e++) {
    int s = srcs[e];
    u16x8 v = *(const u16x8*)&xb[(size_t)s * DH_ + c0];
    float w = rso[s];
#pragma unroll
    for (int j = 0; j < 8; j++) acc[j] += bf2f(v[j]) * w;
  }
  float wi = rs_in[r * TOTAL_ + node];
  u16x8 o;
#pragma unroll
  for (int j = 0; j < 8; j++) o[j] = f2bf(acc[j] * wi);
  *(u16x8*)&aggB[(size_t)node * 1024 + r * DH_ + c0] = o;
}

// ---------------- MFMA GEMM: C[32768,256] = A[32768,1024] @ W ----------------
// A row-major bf16, Bt = W^T [256 cols][1024 k] bf16. 128x128 tile, BK=32.
// MODE 0: out = bf16(relu(acc+bias)); MODE 1: out = f32 acc+bias.
template <int MODE>
__global__ __launch_bounds__(256) void gemm_mfma(
    const unsigned short* __restrict__ A, const unsigned short* __restrict__ Bt,
    const float* __restrict__ bias, unsigned short* __restrict__ outb,
    float* __restrict__ outf) {
  __shared__ unsigned short As[128][40];  // 40-elem stride: 80B rows, 16B aligned
  __shared__ unsigned short Bs[128][40];
  int t = threadIdx.x;
  int row0 = blockIdx.x * 128, col0 = blockIdx.y * 128;
  int wid = t >> 6, lane = t & 63;
  int wm = wid >> 1, wn = wid & 1;
  int lr = lane & 15, lk = (lane >> 4) * 8;
  f32x4 acc[4][4] = {};
  for (int k0 = 0; k0 < 1024; k0 += 32) {
#pragma unroll
    for (int i = 0; i < 2; i++) {
      int chunk = t + 256 * i;
      int rr = chunk >> 2, kc = (chunk & 3) * 8;
      short8v av = *(const short8v*)&A[(size_t)(row0 + rr) * 1024 + k0 + kc];
      *(short8v*)&As[rr][kc] = av;
      short8v bv = *(const short8v*)&Bt[(size_t)(col0 + rr) * 1024 + k0 + kc];
      *(short8v*)&Bs[rr][kc] = bv;
    }
    __syncthreads();
    short8v afr[4], bfr[4];
#pragma unroll
    for (int m = 0; m < 4; m++) afr[m] = *(const short8v*)&As[wm * 64 + m * 16 + lr][lk];
#pragma unroll
    for (int n = 0; n < 4; n++) bfr[n] = *(const short8v*)&Bs[wn * 64 + n * 16 + lr][lk];
#pragma unroll
    for (int m = 0; m < 4; m++)
#pragma unroll
      for (int n = 0; n < 4; n++)
        acc[m][n] = __builtin_amdgcn_mfma_f32_16x16x32_bf16(afr[m], bfr[n], acc[m][n], 0, 0, 0);
    __syncthreads();
  }
  int lq = lane >> 4;
#pragma unroll
  for (int m = 0; m < 4; m++) {
    int row = row0 + wm * 64 + m * 16 + lq * 4;
#pragma unroll
    for (int n = 0; n < 4; n++) {
      int col = col0 + wn * 64 + n * 16 + lr;
      float bv = bias[col];
#pragma unroll
      for (int q = 0; q < 4; q++) {
        float v = acc[m][n][q] + bv;
        if (MODE == 0) {
          v = fmaxf(v, 0.f);
          outb[(size_t)(row + q) * DH_ + col] = f2bf(v);
        } else {
          outf[(size_t)(row + q) * DH_ + col] = v;
        }
      }
    }
  }
}

// ---------------- pooling (2-phase) ----------------

__global__ void cluster_count(const int* __restrict__ node_label, int* __restrict__ ccnt) {
  __shared__ int cnt[C_];
  if (threadIdx.x < C_) cnt[threadIdx.x] = 0;
  __syncthreads();
  for (int n = threadIdx.x; n < NNODE_; n += blockDim.x) atomicAdd(&cnt[node_label[n]], 1);
  __syncthreads();
  if (threadIdx.x < C_) ccnt[threadIdx.x] = cnt[threadIdx.x];
}

// grid (B, 8): per-chunk partial sums. part[ch][b][9][256] (k=0..7 clusters, 8=total)
__global__ __launch_bounds__(256) void pool_part(const float* __restrict__ h2,
                                                 const int* __restrict__ node_label,
                                                 float* __restrict__ part) {
  int b = blockIdx.x, ch = blockIdx.y, d = threadIdx.x;
  __shared__ int slab[128];
  if (d < 128) slab[d] = node_label[ch * 128 + d];
  __syncthreads();
  float a[C_] = {0.f};
  float at = 0.f;
  const float* base = h2 + ((size_t)b * NNODE_ + ch * 128) * DH_ + d;
  for (int n = 0; n < 128; n++) {
    float x = base[(size_t)n * DH_];
    int lab = slab[n];
    at += x;
#pragma unroll
    for (int k = 0; k < C_; k++) a[k] += (lab == k) ? x : 0.f;
  }
  float* pb = part + ((size_t)(ch * B_ + b) * 9) * DH_ + d;
#pragma unroll
  for (int k = 0; k < C_; k++) pb[(size_t)k * DH_] = a[k];
  pb[(size_t)8 * DH_] = at;
}

__global__ __launch_bounds__(256) void pool_fin(const float* __restrict__ part,
                                                const int* __restrict__ feat_label,
                                                const int* __restrict__ ccnt,
                                                float* __restrict__ poolv,
                                                float* __restrict__ hg_raw) {
  int b = blockIdx.x, d = threadIdx.x;
  float s[9];
#pragma unroll
  for (int k = 0; k < 9; k++) s[k] = 0.f;
  for (int ch = 0; ch < 8; ch++) {
    const float* pb = part + ((size_t)(ch * B_ + b) * 9) * DH_ + d;
#pragma unroll
    for (int k = 0; k < 9; k++) s[k] += pb[(size_t)k * DH_];
  }
  int fl = feat_label[d];
#pragma unroll
  for (int k = 0; k < C_; k++) {
    float cntf = fmaxf((float)ccnt[k], 1.f);
    float v = (fl == k) ? (s[k] / cntf) : 0.f;
    poolv[((size_t)k * B_ + b) * DH_ + d] = v;
  }
  hg_raw[(size_t)b * DH_ + d] = s[8] * (1.f / NNODE_);
}

// ---------------- resize / attention / head ----------------

__global__ __launch_bounds__(256) void resize_k(const float* __restrict__ poolv,
                                                const float* __restrict__ Wr,
                                                const float* __restrict__ br,
                                                float* __restrict__ emb_in) {
  int blk = blockIdx.x;
  int key = blk / B_, b = blk % B_;
  int j = threadIdx.x;
  __shared__ float v[DH_];
  v[j] = poolv[((size_t)key * B_ + b) * DH_ + j];
  __syncthreads();
  const float* wrow = Wr + ((size_t)key * DH_ + j) * DH_;
  float s = 0.f;
  for (int d = 0; d < DH_; d++) s += v[d] * wrow[d];
  emb_in[((size_t)b * C_ + key) * DH_ + j] = s + br[key * DH_ + j];
}

__global__ __launch_bounds__(256) void qkv_k(const float* __restrict__ emb_in,
                                             const float* __restrict__ Wq,
                                             const float* __restrict__ Wk,
                                             const float* __restrict__ Wv,
                                             float* __restrict__ q, float* __restrict__ k,
                                             float* __restrict__ v) {
  int b = blockIdx.x, d = threadIdx.x;
  __shared__ float x[C_][DH_];
  for (int c = 0; c < C_; c++) x[c][d] = emb_in[((size_t)b * C_ + c) * DH_ + d];
  __syncthreads();
  for (int c = 0; c < C_; c++) {
    float sq = 0.f, sk = 0.f, sv = 0.f;
    for (int kk = 0; kk < DH_; kk++) {
      float xv = x[c][kk];
      sq += xv * Wq[kk * DH_ + d];
      sk += xv * Wk[kk * DH_ + d];
      sv += xv * Wv[kk * DH_ + d];
    }
    q[((size_t)b * C_ + c) * DH_ + d] = sq;
    k[((size_t)b * C_ + c) * DH_ + d] = sk;
    v[((size_t)b * C_ + c) * DH_ + d] = sv;
  }
}

__global__ __launch_bounds__(256) void attn_k(const float* __restrict__ q,
                                              const float* __restrict__ k,
                                              const float* __restrict__ v,
                                              const float* __restrict__ emb_in,
                                              const float* __restrict__ lin_w,
                                              const float* __restrict__ lin_b,
                                              float* __restrict__ ge) {
  int b = blockIdx.x, t = threadIdx.x;
  __shared__ float qs[C_][DH_], ks[C_][DH_], vs[C_][DH_], os[C_][DH_];
  __shared__ float sc[H_][C_][C_];
  for (int c = 0; c < C_; c++) {
    qs[c][t] = q[((size_t)b * C_ + c) * DH_ + t];
    ks[c][t] = k[((size_t)b * C_ + c) * DH_ + t];
    vs[c][t] = v[((size_t)b * C_ + c) * DH_ + t];
  }
  __syncthreads();
  for (int idx = t; idx < H_ * C_ * C_; idx += 256) {
    int hh = idx / (C_ * C_);
    int qc = (idx / C_) % C_;
    int kc = idx % C_;
    float s = 0.f;
    for (int dd = 0; dd < 32; dd++) s += qs[qc][hh * 32 + dd] * ks[kc][hh * 32 + dd];
    sc[hh][qc][kc] = s * 0.35355339059327373f;
  }
  __syncthreads();
  if (t < H_ * C_) {
    int hh = t / C_, qc = t % C_;
    float m = -1e30f;
    for (int kc = 0; kc < C_; kc++) m = fmaxf(m, sc[hh][qc][kc]);
    float sum = 0.f;
    for (int kc = 0; kc < C_; kc++) { float e = expf(sc[hh][qc][kc] - m); sc[hh][qc][kc] = e; sum += e; }
    float inv = 1.f / sum;
    for (int kc = 0; kc < C_; kc++) sc[hh][qc][kc] *= inv;
  }
  __syncthreads();
  int hh = t >> 5;
  for (int c = 0; c < C_; c++) {
    float s = 0.f;
#pragma unroll
    for (int kc = 0; kc < C_; kc++) s += sc[hh][c][kc] * vs[kc][t];
    os[c][t] = s;
  }
  __syncthreads();
  const float* wrow = lin_w + (size_t)t * DH_;
  float s[C_] = {0.f};
  for (int d2 = 0; d2 < DH_; d2++) {
    float w = wrow[d2];
#pragma unroll
    for (int c = 0; c < C_; c++) s[c] += os[c][d2] * w;
  }
  float lbv = lin_b[t];
  float macc = 0.f;
#pragma unroll
  for (int c = 0; c < C_; c++) {
    float ff = fmaxf(s[c] + lbv, 0.f) + os[c][t];
    macc += ff + emb_in[((size_t)b * C_ + c) * DH_ + t];
  }
  ge[(size_t)b * DH_ + t] = macc * (1.f / C_);
}

__global__ void recon_k(const float* __restrict__ ge, const float* __restrict__ hg_raw,
                        float* __restrict__ out) {
  __shared__ float part[256];
  int t = threadIdx.x;
  float s = 0.f;
  for (int i = t; i < B_ * DH_; i += 256) {
    float d = ge[i] - hg_raw[i] + 1e-6f;
    s += d * d;
  }
  part[t] = s;
  __syncthreads();
  for (int sdl = 128; sdl > 0; sdl >>= 1) {
    if (t < sdl) part[t] += part[t + sdl];
    __syncthreads();
  }
  if (t == 0) out[B_ * NCLS_] = sqrtf(part[0]);
}

__global__ void bn_k(const float* __restrict__ ge, const float* __restrict__ g,
                     const float* __restrict__ be, float* __restrict__ hgn) {
  int d = threadIdx.x;
  float mu = 0.f;
  for (int b = 0; b < B_; b++) mu += ge[b * DH_ + d];
  mu *= (1.f / B_);
  float var = 0.f;
  for (int b = 0; b < B_; b++) { float x = ge[b * DH_ + d] - mu; var += x * x; }
  var *= (1.f / B_);
  float is = rsqrtf(var + 1e-5f);
  float gm = g[d], bt = be[d];
  for (int b = 0; b < B_; b++) hgn[b * DH_ + d] = (ge[b * DH_ + d] - mu) * is * gm + bt;
}

__global__ void logits_k(const float* __restrict__ hgn, const float* __restrict__ cw,
                         const float* __restrict__ cb, float* __restrict__ out) {
  int t = threadIdx.x;
  if (t < B_ * NCLS_) {
    int b = t / NCLS_, j = t % NCLS_;
    float s = cb[j];
    for (int d = 0; d < DH_; d++) s += hgn[b * DH_ + d] * cw[j * DH_ + d];
    out[t] = s;
  }
}

// ---------------- launch ----------------

extern "C" void kernel_launch(void* const* d_in, const int* in_sizes, int n_in,
                              void* d_out, int out_size, void* d_ws, size_t ws_size,
                              hipStream_t stream) {
  const float* h   = (const float*)d_in[0];
  const int* src   = (const int*)d_in[1];
  const int* dst   = (const int*)d_in[2];
  const int* nlab  = (const int*)d_in[3];
  const int* flab  = (const int*)d_in[4];
  const float* W1  = (const float*)d_in[5];
  const float* b1  = (const float*)d_in[6];
  const float* W2  = (const float*)d_in[7];
  const float* b2  = (const float*)d_in[8];
  const float* Wr  = (const float*)d_in[9];
  const float* br  = (const float*)d_in[10];
  const float* Wq  = (const float*)d_in[11];
  const float* Wk  = (const float*)d_in[12];
  const float* Wv  = (const float*)d_in[13];
  const float* lw  = (const float*)d_in[14];
  const float* lb  = (const float*)d_in[15];
  const float* bng = (const float*)d_in[16];
  const float* bnb = (const float*)d_in[17];
  const float* cw  = (const float*)d_in[18];
  const float* cb  = (const float*)d_in[19];
  float* out = (float*)d_out;

  char* p = (char*)d_ws;
  auto alloc = [&](size_t bytes) -> void* {
    void* q = (void*)p;
    p += (bytes + 255) & ~(size_t)255;
    return q;
  };
  // region0: hb [16MB] + h1b [16MB]; later reused as h2 f32 [32MB]
  char* region0 = (char*)alloc((size_t)TOTAL_ * DH_ * 4);
  unsigned short* hb  = (unsigned short*)region0;
  unsigned short* h1b = (unsigned short*)(region0 + (size_t)TOTAL_ * DH_ * 2);
  float* h2 = (float*)region0;

  unsigned short* aggB = (unsigned short*)alloc((size_t)TOTAL_ * 1024 * 2);  // 64MB
  unsigned short* Wt1  = (unsigned short*)alloc((size_t)1024 * DH_ * 2);
  unsigned short* Wt2  = (unsigned short*)alloc((size_t)1024 * DH_ * 2);
  float* bsum1 = (float*)alloc(DH_ * 4);
  float* bsum2 = (float*)alloc(DH_ * 4);
  int* cnt      = (int*)alloc((size_t)2 * R_ * TOTAL_ * 4);
  float* rs_out = (float*)alloc((size_t)R_ * TOTAL_ * 4);
  float* rs_in  = (float*)alloc((size_t)R_ * TOTAL_ * 4);
  int* csr_off  = (int*)alloc((size_t)R_ * (TOTAL_ + 1) * 4);
  int* csr_pos  = (int*)alloc((size_t)R_ * TOTAL_ * 4);
  int* csr_src  = (int*)alloc((size_t)R_ * E_ * 4);
  int* ccnt     = (int*)alloc(64);
  float* part   = (float*)alloc((size_t)8 * B_ * 9 * DH_ * 4);  // 2.4MB
  float* poolv  = (float*)alloc((size_t)C_ * B_ * DH_ * 4);
  float* hg_raw = (float*)alloc((size_t)B_ * DH_ * 4);
  float* emb_in = (float*)alloc((size_t)B_ * C_ * DH_ * 4);
  float* qb     = (float*)alloc((size_t)B_ * C_ * DH_ * 4);
  float* kb     = (float*)alloc((size_t)B_ * C_ * DH_ * 4);
  float* vb     = (float*)alloc((size_t)B_ * C_ * DH_ * 4);
  float* ge     = (float*)alloc((size_t)B_ * DH_ * 4);
  float* hgn    = (float*)alloc((size_t)B_ * DH_ * 4);

  int* cnt_out = cnt;
  int* cnt_in  = cnt + R_ * TOTAL_;

  // graph prep
  zero_i32<<<(2 * R_ * TOTAL_ + 255) / 256, 256, 0, stream>>>(cnt, 2 * R_ * TOTAL_);
  count_deg<<<(R_ * E_ + 255) / 256, 256, 0, stream>>>(src, dst, cnt_out, cnt_in);
  deg_rsqrt<<<(R_ * TOTAL_ + 255) / 256, 256, 0, stream>>>(cnt_out, cnt_in, rs_out, rs_in);
  scan_counts<<<R_, 1024, 0, stream>>>(cnt_in, csr_off, csr_pos);
  build_csr<<<(R_ * E_ + 255) / 256, 256, 0, stream>>>(src, dst, csr_pos, csr_src);

  // weight/bias prep
  wconv<<<1024, 256, 0, stream>>>(W1, Wt1);
  wconv<<<1024, 256, 0, stream>>>(W2, Wt2);
  bias_sum<<<1, 256, 0, stream>>>(b1, bsum1);
  bias_sum<<<1, 256, 0, stream>>>(b2, bsum2);

  // layer 1
  hconv<<<TOTAL_ * DH_ / 4 / 256, 256, 0, stream>>>(h, hb);
  aggregate_b<<<dim3(TOTAL_ / 8, R_), 256, 0, stream>>>(hb, csr_off, csr_src, rs_out, rs_in, aggB);
  gemm_mfma<0><<<dim3(TOTAL_ / 128, 2), 256, 0, stream>>>(aggB, Wt1, bsum1, h1b, nullptr);

  // layer 2
  aggregate_b<<<dim3(TOTAL_ / 8, R_), 256, 0, stream>>>(h1b, csr_off, csr_src, rs_out, rs_in, aggB);
  gemm_mfma<1><<<dim3(TOTAL_ / 128, 2), 256, 0, stream>>>(aggB, Wt2, bsum2, nullptr, h2);

  // pooling + attention + head
  cluster_count<<<1, 256, 0, stream>>>(nlab, ccnt);
  pool_part<<<dim3(B_, 8), 256, 0, stream>>>(h2, nlab, part);
  pool_fin<<<B_, 256, 0, stream>>>(part, flab, ccnt, poolv, hg_raw);
  resize_k<<<C_ * B_, 256, 0, stream>>>(poolv, Wr, br, emb_in);
  qkv_k<<<B_, 256, 0, stream>>>(emb_in, Wq, Wk, Wv, qb, kb, vb);
  attn_k<<<B_, 256, 0, stream>>>(qb, kb, vb, emb_in, lw, lb, ge);
  recon_k<<<1, 256, 0, stream>>>(ge, hg_raw, out);
  bn_k<<<1, 256, 0, stream>>>(ge, bng, bnb, hgn);
  logits_k<<<1, 320, 0, stream>>>(hgn, cw, cb, out);
}

// Round 3
// 534.658 us; speedup vs baseline: 2.6683x; 1.0524x over previous
//
#include <hip/hip_runtime.h>
#include <math.h>

#define R_ 4
#define TOTAL_ 32768
#define NNODE_ 1024
#define B_ 32
#define DH_ 256
#define C_ 8
#define H_ 8
#define NCLS_ 10
#define E_ 262144

typedef __attribute__((ext_vector_type(8))) short short8v;
typedef __attribute__((ext_vector_type(8))) unsigned short u16x8;
typedef __attribute__((ext_vector_type(4))) float f32x4;
typedef __attribute__((ext_vector_type(2))) float f32x2;
typedef __attribute__((ext_vector_type(2))) unsigned int uint2v;

__device__ inline unsigned short f2bf(float f) {
  unsigned int u = __builtin_bit_cast(unsigned int, f);
  u += 0x7FFF + ((u >> 16) & 1);
  return (unsigned short)(u >> 16);
}
__device__ inline float bf2f(unsigned short s) {
  return __builtin_bit_cast(float, (unsigned int)s << 16);
}

// ---------------- graph prep ----------------

__global__ void count_deg(const int* __restrict__ src, const int* __restrict__ dst,
                          int* __restrict__ cnt_out, int* __restrict__ cnt_in) {
  int i = blockIdx.x * blockDim.x + threadIdx.x;
  if (i < R_ * E_) {
    int r = i / E_;
    atomicAdd(&cnt_out[r * TOTAL_ + src[i]], 1);
    atomicAdd(&cnt_in[r * TOTAL_ + dst[i]], 1);
  }
}

__global__ void deg_rsqrt(const int* __restrict__ cnt_out, const int* __restrict__ cnt_in,
                          float* __restrict__ rs_out, float* __restrict__ rs_in) {
  int i = blockIdx.x * blockDim.x + threadIdx.x;
  if (i < R_ * TOTAL_) {
    rs_out[i] = rsqrtf((float)(cnt_out[i] + 1));
    rs_in[i]  = rsqrtf((float)(cnt_in[i] + 1));
  }
}

__global__ __launch_bounds__(1024) void scan_counts(const int* __restrict__ cnt_in,
                                                    int* __restrict__ off,
                                                    int* __restrict__ pos) {
  int r = blockIdx.x;
  const int* c = cnt_in + r * TOTAL_;
  int* o = off + r * (TOTAL_ + 1);
  __shared__ int part[1024];
  int t = threadIdx.x;
  int base = t * 32;
  int loc[32];
  int s = 0;
#pragma unroll
  for (int j = 0; j < 32; j++) { loc[j] = c[base + j]; s += loc[j]; }
  part[t] = s;
  __syncthreads();
  for (int d = 1; d < 1024; d <<= 1) {
    int v = (t >= d) ? part[t - d] : 0;
    __syncthreads();
    part[t] += v;
    __syncthreads();
  }
  int run = (t == 0) ? 0 : part[t - 1];
#pragma unroll
  for (int j = 0; j < 32; j++) {
    o[base + j] = run;
    pos[r * TOTAL_ + base + j] = run;
    run += loc[j];
  }
  if (t == 1023) o[TOTAL_] = run;
}

__global__ void build_csr(const int* __restrict__ src, const int* __restrict__ dst,
                          int* __restrict__ pos, int* __restrict__ csr_src) {
  int i = blockIdx.x * blockDim.x + threadIdx.x;
  if (i < R_ * E_) {
    int r = i / E_;
    int slot = atomicAdd(&pos[r * TOTAL_ + dst[i]], 1);
    csr_src[(size_t)r * E_ + slot] = src[i];
  }
}

// ---------------- conversions ----------------

// f32 -> fp8 e4m3, 8 elems/thread
__global__ void hconv8(const float* __restrict__ x, unsigned int* __restrict__ xq) {
  size_t i = (size_t)blockIdx.x * blockDim.x + threadIdx.x;
  float4 a = ((const float4*)x)[2 * i];
  float4 b = ((const float4*)x)[2 * i + 1];
  unsigned int lo = 0, hi = 0;
  lo = __builtin_amdgcn_cvt_pk_fp8_f32(a.x, a.y, lo, false);
  lo = __builtin_amdgcn_cvt_pk_fp8_f32(a.z, a.w, lo, true);
  hi = __builtin_amdgcn_cvt_pk_fp8_f32(b.x, b.y, hi, false);
  hi = __builtin_amdgcn_cvt_pk_fp8_f32(b.z, b.w, hi, true);
  uint2v o; o[0] = lo; o[1] = hi;
  *(uint2v*)&xq[2 * i] = o;
}

// stacked W [1024,256] f32 -> Wt [256,1024] bf16, both layers in one launch
__global__ void wconv2(const float* __restrict__ W1, const float* __restrict__ W2,
                       unsigned short* __restrict__ T1, unsigned short* __restrict__ T2) {
  int i = blockIdx.x * blockDim.x + threadIdx.x;  // 0..524287
  const float* W = (i < 262144) ? W1 : W2;
  unsigned short* T = (i < 262144) ? T1 : T2;
  int j = i & 262143;
  int k = j >> 8, c = j & 255;
  T[(size_t)c * 1024 + k] = f2bf(W[j]);
}

__global__ void bias_sum2(const float* __restrict__ b1, const float* __restrict__ b2,
                          float* __restrict__ s1, float* __restrict__ s2) {
  const float* b = blockIdx.x ? b2 : b1;
  float* s = blockIdx.x ? s2 : s1;
  int d = threadIdx.x;
  s[d] = b[d] + b[DH_ + d] + b[2 * DH_ + d] + b[3 * DH_ + d];
}

// ---------------- aggregation (fp8 gather) ----------------
// grid (TOTAL/8, R); 32 lanes per node, 8 fp8 bytes per lane
__global__ __launch_bounds__(256) void aggregate_f8(
    const unsigned int* __restrict__ xq, const int* __restrict__ csr_off,
    const int* __restrict__ csr_src, const float* __restrict__ rs_out,
    const float* __restrict__ rs_in, unsigned short* __restrict__ aggB) {
  int r = blockIdx.y;
  int node = blockIdx.x * 8 + (threadIdx.x >> 5);
  int lane5 = threadIdx.x & 31;
  const int* offr = csr_off + r * (TOTAL_ + 1);
  const int* srcs = csr_src + (size_t)r * E_;
  const float* rso = rs_out + r * TOTAL_;
  float acc[8];
  {
    uint2v v = *(const uint2v*)&xq[(size_t)node * 64 + lane5 * 2];
    float w = rso[node];
    f32x2 p;
    p = __builtin_amdgcn_cvt_pk_f32_fp8(v[0], false); acc[0] = p[0] * w; acc[1] = p[1] * w;
    p = __builtin_amdgcn_cvt_pk_f32_fp8(v[0], true);  acc[2] = p[0] * w; acc[3] = p[1] * w;
    p = __builtin_amdgcn_cvt_pk_f32_fp8(v[1], false); acc[4] = p[0] * w; acc[5] = p[1] * w;
    p = __builtin_amdgcn_cvt_pk_f32_fp8(v[1], true);  acc[6] = p[0] * w; acc[7] = p[1] * w;
  }
  int e0 = offr[node], e1 = offr[node + 1];
  int sN = (e0 < e1) ? srcs[e0] : 0;
  for (int e = e0; e < e1; e++) {
    int s = sN;
    if (e + 1 < e1) sN = srcs[e + 1];
    float w = rso[s];
    uint2v v = *(const uint2v*)&xq[(size_t)s * 64 + lane5 * 2];
    f32x2 p;
    p = __builtin_amdgcn_cvt_pk_f32_fp8(v[0], false); acc[0] += p[0] * w; acc[1] += p[1] * w;
    p = __builtin_amdgcn_cvt_pk_f32_fp8(v[0], true);  acc[2] += p[0] * w; acc[3] += p[1] * w;
    p = __builtin_amdgcn_cvt_pk_f32_fp8(v[1], false); acc[4] += p[0] * w; acc[5] += p[1] * w;
    p = __builtin_amdgcn_cvt_pk_f32_fp8(v[1], true);  acc[6] += p[0] * w; acc[7] += p[1] * w;
  }
  float wi = rs_in[r * TOTAL_ + node];
  u16x8 o;
#pragma unroll
  for (int j = 0; j < 8; j++) o[j] = f2bf(acc[j] * wi);
  *(u16x8*)&aggB[(size_t)node * 1024 + r * DH_ + lane5 * 8] = o;
}

// ---------------- MFMA GEMM: C[32768,256] = A[32768,1024] @ W ----------------
// MODE 0: out8 = fp8(relu(acc+bias)); MODE 1: out16 = bf16(acc+bias).
template <int MODE>
__global__ __launch_bounds__(256) void gemm_mfma(
    const unsigned short* __restrict__ A, const unsigned short* __restrict__ Bt,
    const float* __restrict__ bias, unsigned char* __restrict__ out8,
    unsigned short* __restrict__ out16) {
  __shared__ unsigned short As[128][40];
  __shared__ unsigned short Bs[128][40];
  int t = threadIdx.x;
  int row0 = blockIdx.x * 128, col0 = blockIdx.y * 128;
  int wid = t >> 6, lane = t & 63;
  int wm = wid >> 1, wn = wid & 1;
  int lr = lane & 15, lk = (lane >> 4) * 8;
  f32x4 acc[4][4] = {};
  for (int k0 = 0; k0 < 1024; k0 += 32) {
#pragma unroll
    for (int i = 0; i < 2; i++) {
      int chunk = t + 256 * i;
      int rr = chunk >> 2, kc = (chunk & 3) * 8;
      short8v av = *(const short8v*)&A[(size_t)(row0 + rr) * 1024 + k0 + kc];
      *(short8v*)&As[rr][kc] = av;
      short8v bv = *(const short8v*)&Bt[(size_t)(col0 + rr) * 1024 + k0 + kc];
      *(short8v*)&Bs[rr][kc] = bv;
    }
    __syncthreads();
    short8v afr[4], bfr[4];
#pragma unroll
    for (int m = 0; m < 4; m++) afr[m] = *(const short8v*)&As[wm * 64 + m * 16 + lr][lk];
#pragma unroll
    for (int n = 0; n < 4; n++) bfr[n] = *(const short8v*)&Bs[wn * 64 + n * 16 + lr][lk];
#pragma unroll
    for (int m = 0; m < 4; m++)
#pragma unroll
      for (int n = 0; n < 4; n++)
        acc[m][n] = __builtin_amdgcn_mfma_f32_16x16x32_bf16(afr[m], bfr[n], acc[m][n], 0, 0, 0);
    __syncthreads();
  }
  int lq = lane >> 4;
#pragma unroll
  for (int m = 0; m < 4; m++) {
    int row = row0 + wm * 64 + m * 16 + lq * 4;
#pragma unroll
    for (int n = 0; n < 4; n++) {
      int col = col0 + wn * 64 + n * 16 + lr;
      float bv = bias[col];
#pragma unroll
      for (int q = 0; q < 4; q++) {
        float v = acc[m][n][q] + bv;
        if (MODE == 0) {
          v = fmaxf(v, 0.f);
          int b8 = __builtin_amdgcn_cvt_pk_fp8_f32(v, 0.f, 0, false);
          out8[(size_t)(row + q) * DH_ + col] = (unsigned char)b8;
        } else {
          out16[(size_t)(row + q) * DH_ + col] = f2bf(v);
        }
      }
    }
  }
}

// ---------------- pooling (2-phase, bf16 h2) ----------------

// grid (B, 8): per-chunk partial sums. part[ch][b][9][256]
__global__ __launch_bounds__(256) void pool_part(const unsigned short* __restrict__ h2b,
                                                 const int* __restrict__ node_label,
                                                 float* __restrict__ part) {
  int b = blockIdx.x, ch = blockIdx.y, d = threadIdx.x;
  __shared__ int slab[128];
  if (d < 128) slab[d] = node_label[ch * 128 + d];
  __syncthreads();
  float a[C_] = {0.f};
  float at = 0.f;
  const unsigned short* base = h2b + ((size_t)b * NNODE_ + ch * 128) * DH_ + d;
  for (int n = 0; n < 128; n++) {
    float x = bf2f(base[(size_t)n * DH_]);
    int lab = slab[n];
    at += x;
#pragma unroll
    for (int k = 0; k < C_; k++) a[k] += (lab == k) ? x : 0.f;
  }
  float* pb = part + ((size_t)(ch * B_ + b) * 9) * DH_ + d;
#pragma unroll
  for (int k = 0; k < C_; k++) pb[(size_t)k * DH_] = a[k];
  pb[(size_t)8 * DH_] = at;
}

__global__ __launch_bounds__(256) void pool_fin(const float* __restrict__ part,
                                                const int* __restrict__ node_label,
                                                const int* __restrict__ feat_label,
                                                float* __restrict__ poolv,
                                                float* __restrict__ hg_raw) {
  int b = blockIdx.x, d = threadIdx.x;
  __shared__ int cnt[C_];
  if (d < C_) cnt[d] = 0;
  __syncthreads();
  for (int n = d; n < NNODE_; n += 256) atomicAdd(&cnt[node_label[n]], 1);
  __syncthreads();
  float s[9];
#pragma unroll
  for (int k = 0; k < 9; k++) s[k] = 0.f;
  for (int ch = 0; ch < 8; ch++) {
    const float* pb = part + ((size_t)(ch * B_ + b) * 9) * DH_ + d;
#pragma unroll
    for (int k = 0; k < 9; k++) s[k] += pb[(size_t)k * DH_];
  }
  int fl = feat_label[d];
#pragma unroll
  for (int k = 0; k < C_; k++) {
    float cntf = fmaxf((float)cnt[k], 1.f);
    float v = (fl == k) ? (s[k] / cntf) : 0.f;
    poolv[((size_t)k * B_ + b) * DH_ + d] = v;
  }
  hg_raw[(size_t)b * DH_ + d] = s[8] * (1.f / NNODE_);
}

// ---------------- fused tail: resize + qkv + attention per graph ----------------

__global__ __launch_bounds__(256) void tail_graph(
    const float* __restrict__ poolv, const float* __restrict__ Wr,
    const float* __restrict__ br, const float* __restrict__ Wq,
    const float* __restrict__ Wk, const float* __restrict__ Wv,
    const float* __restrict__ lin_w, const float* __restrict__ lin_b,
    float* __restrict__ ge) {
  int b = blockIdx.x, t = threadIdx.x;
  __shared__ float pl[C_][DH_], es[C_][DH_];
  __shared__ float qs[C_][DH_], ks[C_][DH_], vs[C_][DH_], os[C_][DH_];
  __shared__ float sc[H_][C_][C_];
  for (int k = 0; k < C_; k++) pl[k][t] = poolv[((size_t)k * B_ + b) * DH_ + t];
  __syncthreads();
  // resize: es[key][t] = pl[key] . Wr[key][t][:] + br[key][t]
  for (int key = 0; key < C_; key++) {
    const float* wrow = Wr + ((size_t)key * DH_ + t) * DH_;
    float s = 0.f;
    for (int d = 0; d < DH_; d++) s += pl[key][d] * wrow[d];
    es[key][t] = s + br[key * DH_ + t];
  }
  __syncthreads();
  // qkv
  for (int c = 0; c < C_; c++) {
    float sq = 0.f, sk = 0.f, sv = 0.f;
    for (int kk = 0; kk < DH_; kk++) {
      float xv = es[c][kk];
      sq += xv * Wq[kk * DH_ + t];
      sk += xv * Wk[kk * DH_ + t];
      sv += xv * Wv[kk * DH_ + t];
    }
    qs[c][t] = sq; ks[c][t] = sk; vs[c][t] = sv;
  }
  __syncthreads();
  // scores + softmax
  for (int idx = t; idx < H_ * C_ * C_; idx += 256) {
    int hh = idx / (C_ * C_);
    int qc = (idx / C_) % C_;
    int kc = idx % C_;
    float s = 0.f;
    for (int dd = 0; dd < 32; dd++) s += qs[qc][hh * 32 + dd] * ks[kc][hh * 32 + dd];
    sc[hh][qc][kc] = s * 0.35355339059327373f;
  }
  __syncthreads();
  if (t < H_ * C_) {
    int hh = t / C_, qc = t % C_;
    float m = -1e30f;
    for (int kc = 0; kc < C_; kc++) m = fmaxf(m, sc[hh][qc][kc]);
    float sum = 0.f;
    for (int kc = 0; kc < C_; kc++) { float e = expf(sc[hh][qc][kc] - m); sc[hh][qc][kc] = e; sum += e; }
    float inv = 1.f / sum;
    for (int kc = 0; kc < C_; kc++) sc[hh][qc][kc] *= inv;
  }
  __syncthreads();
  int hh = t >> 5;
  for (int c = 0; c < C_; c++) {
    float s = 0.f;
#pragma unroll
    for (int kc = 0; kc < C_; kc++) s += sc[hh][c][kc] * vs[kc][t];
    os[c][t] = s;
  }
  __syncthreads();
  const float* wrow = lin_w + (size_t)t * DH_;
  float s[C_] = {0.f};
  for (int d2 = 0; d2 < DH_; d2++) {
    float w = wrow[d2];
#pragma unroll
    for (int c = 0; c < C_; c++) s[c] += os[c][d2] * w;
  }
  float lbv = lin_b[t];
  float macc = 0.f;
#pragma unroll
  for (int c = 0; c < C_; c++) {
    float ff = fmaxf(s[c] + lbv, 0.f) + os[c][t];
    macc += ff + es[c][t];
  }
  ge[(size_t)b * DH_ + t] = macc * (1.f / C_);
}

// ---------------- fused tail: recon + batchnorm + logits (1 block) ----------------

__global__ __launch_bounds__(256) void tail_final(
    const float* __restrict__ ge, const float* __restrict__ hg_raw,
    const float* __restrict__ g, const float* __restrict__ be,
    const float* __restrict__ cw, const float* __restrict__ cb,
    float* __restrict__ out) {
  int t = threadIdx.x;
  __shared__ float hgn[B_][DH_];
  __shared__ float red[256];
  float mu = 0.f;
  for (int b = 0; b < B_; b++) mu += ge[b * DH_ + t];
  mu *= (1.f / B_);
  float var = 0.f;
  for (int b = 0; b < B_; b++) { float x = ge[b * DH_ + t] - mu; var += x * x; }
  var *= (1.f / B_);
  float is = rsqrtf(var + 1e-5f);
  float gm = g[t], bt = be[t];
  for (int b = 0; b < B_; b++) hgn[b][t] = (ge[b * DH_ + t] - mu) * is * gm + bt;
  float s = 0.f;
  for (int i = t; i < B_ * DH_; i += 256) {
    float d = ge[i] - hg_raw[i] + 1e-6f;
    s += d * d;
  }
  red[t] = s;
  __syncthreads();
  for (int w = 128; w > 0; w >>= 1) {
    if (t < w) red[t] += red[t + w];
    __syncthreads();
  }
  if (t == 0) out[B_ * NCLS_] = sqrtf(red[0]);
  for (int o = t; o < B_ * NCLS_; o += 256) {
    int b = o / NCLS_, j = o % NCLS_;
    float sl = cb[j];
    for (int d = 0; d < DH_; d++) sl += hgn[b][d] * cw[j * DH_ + d];
    out[o] = sl;
  }
}

// ---------------- launch ----------------

extern "C" void kernel_launch(void* const* d_in, const int* in_sizes, int n_in,
                              void* d_out, int out_size, void* d_ws, size_t ws_size,
                              hipStream_t stream) {
  const float* h   = (const float*)d_in[0];
  const int* src   = (const int*)d_in[1];
  const int* dst   = (const int*)d_in[2];
  const int* nlab  = (const int*)d_in[3];
  const int* flab  = (const int*)d_in[4];
  const float* W1  = (const float*)d_in[5];
  const float* b1  = (const float*)d_in[6];
  const float* W2  = (const float*)d_in[7];
  const float* b2  = (const float*)d_in[8];
  const float* Wr  = (const float*)d_in[9];
  const float* br  = (const float*)d_in[10];
  const float* Wq  = (const float*)d_in[11];
  const float* Wk  = (const float*)d_in[12];
  const float* Wv  = (const float*)d_in[13];
  const float* lw  = (const float*)d_in[14];
  const float* lb  = (const float*)d_in[15];
  const float* bng = (const float*)d_in[16];
  const float* bnb = (const float*)d_in[17];
  const float* cw  = (const float*)d_in[18];
  const float* cb  = (const float*)d_in[19];
  float* out = (float*)d_out;

  char* p = (char*)d_ws;
  auto alloc = [&](size_t bytes) -> void* {
    void* q = (void*)p;
    p += (bytes + 255) & ~(size_t)255;
    return q;
  };
  unsigned int* xq    = (unsigned int*)alloc((size_t)TOTAL_ * DH_);        // 8MB fp8
  unsigned char* h1q  = (unsigned char*)alloc((size_t)TOTAL_ * DH_);       // 8MB fp8
  unsigned short* h2b = (unsigned short*)alloc((size_t)TOTAL_ * DH_ * 2);  // 16MB bf16
  unsigned short* aggB = (unsigned short*)alloc((size_t)TOTAL_ * 1024 * 2);
  unsigned short* Wt1  = (unsigned short*)alloc((size_t)1024 * DH_ * 2);
  unsigned short* Wt2  = (unsigned short*)alloc((size_t)1024 * DH_ * 2);
  float* bsum1 = (float*)alloc(DH_ * 4);
  float* bsum2 = (float*)alloc(DH_ * 4);
  int* cnt      = (int*)alloc((size_t)2 * R_ * TOTAL_ * 4);
  float* rs_out = (float*)alloc((size_t)R_ * TOTAL_ * 4);
  float* rs_in  = (float*)alloc((size_t)R_ * TOTAL_ * 4);
  int* csr_off  = (int*)alloc((size_t)R_ * (TOTAL_ + 1) * 4);
  int* csr_pos  = (int*)alloc((size_t)R_ * TOTAL_ * 4);
  int* csr_src  = (int*)alloc((size_t)R_ * E_ * 4);
  float* part   = (float*)alloc((size_t)8 * B_ * 9 * DH_ * 4);
  float* poolv  = (float*)alloc((size_t)C_ * B_ * DH_ * 4);
  float* hg_raw = (float*)alloc((size_t)B_ * DH_ * 4);
  float* ge     = (float*)alloc((size_t)B_ * DH_ * 4);

  int* cnt_out = cnt;
  int* cnt_in  = cnt + R_ * TOTAL_;

  // graph prep
  hipMemsetAsync(cnt, 0, (size_t)2 * R_ * TOTAL_ * 4, stream);
  count_deg<<<(R_ * E_ + 255) / 256, 256, 0, stream>>>(src, dst, cnt_out, cnt_in);
  deg_rsqrt<<<(R_ * TOTAL_ + 255) / 256, 256, 0, stream>>>(cnt_out, cnt_in, rs_out, rs_in);
  scan_counts<<<R_, 1024, 0, stream>>>(cnt_in, csr_off, csr_pos);
  build_csr<<<(R_ * E_ + 255) / 256, 256, 0, stream>>>(src, dst, csr_pos, csr_src);

  // weight/bias/input prep
  wconv2<<<2048, 256, 0, stream>>>(W1, W2, Wt1, Wt2);
  bias_sum2<<<2, 256, 0, stream>>>(b1, b2, bsum1, bsum2);
  hconv8<<<TOTAL_ * DH_ / 8 / 256, 256, 0, stream>>>(h, xq);

  // layer 1
  aggregate_f8<<<dim3(TOTAL_ / 8, R_), 256, 0, stream>>>(xq, csr_off, csr_src, rs_out, rs_in, aggB);
  gemm_mfma<0><<<dim3(TOTAL_ / 128, 2), 256, 0, stream>>>(aggB, Wt1, bsum1, h1q, nullptr);

  // layer 2
  aggregate_f8<<<dim3(TOTAL_ / 8, R_), 256, 0, stream>>>((const unsigned int*)h1q, csr_off, csr_src, rs_out, rs_in, aggB);
  gemm_mfma<1><<<dim3(TOTAL_ / 128, 2), 256, 0, stream>>>(aggB, Wt2, bsum2, nullptr, h2b);

  // pooling + fused tail
  pool_part<<<dim3(B_, 8), 256, 0, stream>>>(h2b, nlab, part);
  pool_fin<<<B_, 256, 0, stream>>>(part, nlab, flab, poolv, hg_raw);
  tail_graph<<<B_, 256, 0, stream>>>(poolv, Wr, br, Wq, Wk, Wv, lw, lb, ge);
  tail_final<<<1, 256, 0, stream>>>(ge, hg_raw, bng, bnb, cw, cb, out);
}

// Round 4
// 440.634 us; speedup vs baseline: 3.2376x; 1.2134x over previous
//
#include <hip/hip_runtime.h>
#include <math.h>

#define R_ 4
#define TOTAL_ 32768
#define NNODE_ 1024
#define B_ 32
#define DH_ 256
#define C_ 8
#define H_ 8
#define NCLS_ 10
#define E_ 262144

typedef __attribute__((ext_vector_type(8))) short short8v;
typedef __attribute__((ext_vector_type(8))) unsigned short u16x8;
typedef __attribute__((ext_vector_type(4))) float f32x4;
typedef __attribute__((ext_vector_type(2))) float f32x2;
typedef __attribute__((ext_vector_type(2))) unsigned int uint2v;

__device__ inline unsigned short f2bf(float f) {
  unsigned int u = __builtin_bit_cast(unsigned int, f);
  u += 0x7FFF + ((u >> 16) & 1);
  return (unsigned short)(u >> 16);
}
__device__ inline float bf2f(unsigned short s) {
  return __builtin_bit_cast(float, (unsigned int)s << 16);
}

// ---------------- graph prep ----------------

__global__ void count_deg(const int* __restrict__ src, const int* __restrict__ dst,
                          int* __restrict__ cnt_out, int* __restrict__ cnt_in) {
  int i = blockIdx.x * blockDim.x + threadIdx.x;
  if (i < R_ * E_) {
    int r = i / E_;
    atomicAdd(&cnt_out[r * TOTAL_ + src[i]], 1);
    atomicAdd(&cnt_in[r * TOTAL_ + dst[i]], 1);
  }
}

__global__ void deg_rsqrt(const int* __restrict__ cnt_out, const int* __restrict__ cnt_in,
                          float* __restrict__ rs_out, float* __restrict__ rs_in) {
  int i = blockIdx.x * blockDim.x + threadIdx.x;
  if (i < R_ * TOTAL_) {
    rs_out[i] = rsqrtf((float)(cnt_out[i] + 1));
    rs_in[i]  = rsqrtf((float)(cnt_in[i] + 1));
  }
}

__global__ __launch_bounds__(1024) void scan_counts(const int* __restrict__ cnt_in,
                                                    int* __restrict__ off,
                                                    int* __restrict__ pos) {
  int r = blockIdx.x;
  const int* c = cnt_in + r * TOTAL_;
  int* o = off + r * (TOTAL_ + 1);
  __shared__ int part[1024];
  int t = threadIdx.x;
  int base = t * 32;
  int loc[32];
  int s = 0;
#pragma unroll
  for (int j = 0; j < 32; j++) { loc[j] = c[base + j]; s += loc[j]; }
  part[t] = s;
  __syncthreads();
  for (int d = 1; d < 1024; d <<= 1) {
    int v = (t >= d) ? part[t - d] : 0;
    __syncthreads();
    part[t] += v;
    __syncthreads();
  }
  int run = (t == 0) ? 0 : part[t - 1];
#pragma unroll
  for (int j = 0; j < 32; j++) {
    o[base + j] = run;
    pos[r * TOTAL_ + base + j] = run;
    run += loc[j];
  }
  if (t == 1023) o[TOTAL_] = run;
}

__global__ void build_csr(const int* __restrict__ src, const int* __restrict__ dst,
                          int* __restrict__ pos, int* __restrict__ csr_src) {
  int i = blockIdx.x * blockDim.x + threadIdx.x;
  if (i < R_ * E_) {
    int r = i / E_;
    int slot = atomicAdd(&pos[r * TOTAL_ + dst[i]], 1);
    csr_src[(size_t)r * E_ + slot] = src[i];
  }
}

// ---------------- conversions ----------------

__global__ void hconv8(const float* __restrict__ x, unsigned int* __restrict__ xq) {
  size_t i = (size_t)blockIdx.x * blockDim.x + threadIdx.x;
  float4 a = ((const float4*)x)[2 * i];
  float4 b = ((const float4*)x)[2 * i + 1];
  unsigned int lo = 0, hi = 0;
  lo = __builtin_amdgcn_cvt_pk_fp8_f32(a.x, a.y, lo, false);
  lo = __builtin_amdgcn_cvt_pk_fp8_f32(a.z, a.w, lo, true);
  hi = __builtin_amdgcn_cvt_pk_fp8_f32(b.x, b.y, hi, false);
  hi = __builtin_amdgcn_cvt_pk_fp8_f32(b.z, b.w, hi, true);
  uint2v o; o[0] = lo; o[1] = hi;
  *(uint2v*)&xq[2 * i] = o;
}

// stacked W [1024,256] f32 -> Wt [256,1024] bf16, both layers in one launch
__global__ void wconv2(const float* __restrict__ W1, const float* __restrict__ W2,
                       unsigned short* __restrict__ T1, unsigned short* __restrict__ T2) {
  int i = blockIdx.x * blockDim.x + threadIdx.x;  // 0..524287
  const float* W = (i < 262144) ? W1 : W2;
  unsigned short* T = (i < 262144) ? T1 : T2;
  int j = i & 262143;
  int k = j >> 8, c = j & 255;
  T[(size_t)c * 1024 + k] = f2bf(W[j]);
}

__global__ void bias_sum2(const float* __restrict__ b1, const float* __restrict__ b2,
                          float* __restrict__ s1, float* __restrict__ s2) {
  const float* b = blockIdx.x ? b2 : b1;
  float* s = blockIdx.x ? s2 : s1;
  int d = threadIdx.x;
  s[d] = b[d] + b[DH_ + d] + b[2 * DH_ + d] + b[3 * DH_ + d];
}

// transpose Wr (8 mats) + lin_w (1 mat), each 256x256
__global__ void transpose_mats(const float* __restrict__ Wr, const float* __restrict__ lw,
                               float* __restrict__ Wrt, float* __restrict__ lwt) {
  int i = blockIdx.x * blockDim.x + threadIdx.x;  // 9*65536
  int m = i >> 16, j = i & 65535;
  int row = j >> 8, col = j & 255;
  float v = (m < 8) ? Wr[(size_t)m * 65536 + j] : lw[j];
  float* T = (m < 8) ? (Wrt + (size_t)m * 65536) : lwt;
  T[col * 256 + row] = v;
}

// ---------------- aggregation (fp8 gather, 2-way edge unroll) ----------------
__global__ __launch_bounds__(256) void aggregate_f8(
    const unsigned int* __restrict__ xq, const int* __restrict__ csr_off,
    const int* __restrict__ csr_src, const float* __restrict__ rs_out,
    const float* __restrict__ rs_in, unsigned short* __restrict__ aggB) {
  int r = blockIdx.y;
  int node = blockIdx.x * 8 + (threadIdx.x >> 5);
  int lane5 = threadIdx.x & 31;
  const int* offr = csr_off + r * (TOTAL_ + 1);
  const int* srcs = csr_src + (size_t)r * E_;
  const float* rso = rs_out + r * TOTAL_;
  float acc[8];
  {
    uint2v v = *(const uint2v*)&xq[(size_t)node * 64 + lane5 * 2];
    float w = rso[node];
    f32x2 p;
    p = __builtin_amdgcn_cvt_pk_f32_fp8(v[0], false); acc[0] = p[0] * w; acc[1] = p[1] * w;
    p = __builtin_amdgcn_cvt_pk_f32_fp8(v[0], true);  acc[2] = p[0] * w; acc[3] = p[1] * w;
    p = __builtin_amdgcn_cvt_pk_f32_fp8(v[1], false); acc[4] = p[0] * w; acc[5] = p[1] * w;
    p = __builtin_amdgcn_cvt_pk_f32_fp8(v[1], true);  acc[6] = p[0] * w; acc[7] = p[1] * w;
  }
  int e0 = offr[node], e1 = offr[node + 1];
  int e = e0;
  for (; e + 2 <= e1; e += 2) {
    int s0 = srcs[e], s1 = srcs[e + 1];
    uint2v v0 = *(const uint2v*)&xq[(size_t)s0 * 64 + lane5 * 2];
    uint2v v1 = *(const uint2v*)&xq[(size_t)s1 * 64 + lane5 * 2];
    float w0 = rso[s0], w1 = rso[s1];
    f32x2 p;
    p = __builtin_amdgcn_cvt_pk_f32_fp8(v0[0], false); acc[0] += p[0] * w0; acc[1] += p[1] * w0;
    p = __builtin_amdgcn_cvt_pk_f32_fp8(v0[0], true);  acc[2] += p[0] * w0; acc[3] += p[1] * w0;
    p = __builtin_amdgcn_cvt_pk_f32_fp8(v0[1], false); acc[4] += p[0] * w0; acc[5] += p[1] * w0;
    p = __builtin_amdgcn_cvt_pk_f32_fp8(v0[1], true);  acc[6] += p[0] * w0; acc[7] += p[1] * w0;
    p = __builtin_amdgcn_cvt_pk_f32_fp8(v1[0], false); acc[0] += p[0] * w1; acc[1] += p[1] * w1;
    p = __builtin_amdgcn_cvt_pk_f32_fp8(v1[0], true);  acc[2] += p[0] * w1; acc[3] += p[1] * w1;
    p = __builtin_amdgcn_cvt_pk_f32_fp8(v1[1], false); acc[4] += p[0] * w1; acc[5] += p[1] * w1;
    p = __builtin_amdgcn_cvt_pk_f32_fp8(v1[1], true);  acc[6] += p[0] * w1; acc[7] += p[1] * w1;
  }
  if (e < e1) {
    int s0 = srcs[e];
    uint2v v0 = *(const uint2v*)&xq[(size_t)s0 * 64 + lane5 * 2];
    float w0 = rso[s0];
    f32x2 p;
    p = __builtin_amdgcn_cvt_pk_f32_fp8(v0[0], false); acc[0] += p[0] * w0; acc[1] += p[1] * w0;
    p = __builtin_amdgcn_cvt_pk_f32_fp8(v0[0], true);  acc[2] += p[0] * w0; acc[3] += p[1] * w0;
    p = __builtin_amdgcn_cvt_pk_f32_fp8(v0[1], false); acc[4] += p[0] * w0; acc[5] += p[1] * w0;
    p = __builtin_amdgcn_cvt_pk_f32_fp8(v0[1], true);  acc[6] += p[0] * w0; acc[7] += p[1] * w0;
  }
  float wi = rs_in[r * TOTAL_ + node];
  u16x8 o;
#pragma unroll
  for (int j = 0; j < 8; j++) o[j] = f2bf(acc[j] * wi);
  *(u16x8*)&aggB[(size_t)node * 1024 + r * DH_ + lane5 * 8] = o;
}

// ---------------- MFMA GEMM: C[32768,256] = A[32768,1024] @ W ----------------
template <int MODE>
__global__ __launch_bounds__(256) void gemm_mfma(
    const unsigned short* __restrict__ A, const unsigned short* __restrict__ Bt,
    const float* __restrict__ bias, unsigned char* __restrict__ out8,
    unsigned short* __restrict__ out16) {
  __shared__ unsigned short As[128][40];
  __shared__ unsigned short Bs[128][40];
  int t = threadIdx.x;
  int row0 = blockIdx.x * 128, col0 = blockIdx.y * 128;
  int wid = t >> 6, lane = t & 63;
  int wm = wid >> 1, wn = wid & 1;
  int lr = lane & 15, lk = (lane >> 4) * 8;
  f32x4 acc[4][4] = {};
  for (int k0 = 0; k0 < 1024; k0 += 32) {
#pragma unroll
    for (int i = 0; i < 2; i++) {
      int chunk = t + 256 * i;
      int rr = chunk >> 2, kc = (chunk & 3) * 8;
      short8v av = *(const short8v*)&A[(size_t)(row0 + rr) * 1024 + k0 + kc];
      *(short8v*)&As[rr][kc] = av;
      short8v bv = *(const short8v*)&Bt[(size_t)(col0 + rr) * 1024 + k0 + kc];
      *(short8v*)&Bs[rr][kc] = bv;
    }
    __syncthreads();
    short8v afr[4], bfr[4];
#pragma unroll
    for (int m = 0; m < 4; m++) afr[m] = *(const short8v*)&As[wm * 64 + m * 16 + lr][lk];
#pragma unroll
    for (int n = 0; n < 4; n++) bfr[n] = *(const short8v*)&Bs[wn * 64 + n * 16 + lr][lk];
#pragma unroll
    for (int m = 0; m < 4; m++)
#pragma unroll
      for (int n = 0; n < 4; n++)
        acc[m][n] = __builtin_amdgcn_mfma_f32_16x16x32_bf16(afr[m], bfr[n], acc[m][n], 0, 0, 0);
    __syncthreads();
  }
  int lq = lane >> 4;
#pragma unroll
  for (int m = 0; m < 4; m++) {
    int row = row0 + wm * 64 + m * 16 + lq * 4;
#pragma unroll
    for (int n = 0; n < 4; n++) {
      int col = col0 + wn * 64 + n * 16 + lr;
      float bv = bias[col];
#pragma unroll
      for (int q = 0; q < 4; q++) {
        float v = acc[m][n][q] + bv;
        if (MODE == 0) {
          v = fmaxf(v, 0.f);
          int b8 = __builtin_amdgcn_cvt_pk_fp8_f32(v, 0.f, 0, false);
          out8[(size_t)(row + q) * DH_ + col] = (unsigned char)b8;
        } else {
          out16[(size_t)(row + q) * DH_ + col] = f2bf(v);
        }
      }
    }
  }
}

// ---------------- pooling (2-phase, bf16 h2) ----------------

__global__ __launch_bounds__(256) void pool_part(const unsigned short* __restrict__ h2b,
                                                 const int* __restrict__ node_label,
                                                 float* __restrict__ part) {
  int b = blockIdx.x, ch = blockIdx.y, d = threadIdx.x;
  __shared__ int slab[128];
  if (d < 128) slab[d] = node_label[ch * 128 + d];
  __syncthreads();
  float a[C_] = {0.f};
  float at = 0.f;
  const unsigned short* base = h2b + ((size_t)b * NNODE_ + ch * 128) * DH_ + d;
  for (int n = 0; n < 128; n++) {
    float x = bf2f(base[(size_t)n * DH_]);
    int lab = slab[n];
    at += x;
#pragma unroll
    for (int k = 0; k < C_; k++) a[k] += (lab == k) ? x : 0.f;
  }
  float* pb = part + ((size_t)(ch * B_ + b) * 9) * DH_ + d;
#pragma unroll
  for (int k = 0; k < C_; k++) pb[(size_t)k * DH_] = a[k];
  pb[(size_t)8 * DH_] = at;
}

__global__ __launch_bounds__(256) void pool_fin(const float* __restrict__ part,
                                                const int* __restrict__ node_label,
                                                const int* __restrict__ feat_label,
                                                float* __restrict__ poolv,
                                                float* __restrict__ hg_raw) {
  int b = blockIdx.x, d = threadIdx.x;
  __shared__ int cnt[C_];
  if (d < C_) cnt[d] = 0;
  __syncthreads();
  for (int n = d; n < NNODE_; n += 256) atomicAdd(&cnt[node_label[n]], 1);
  __syncthreads();
  float s[9];
#pragma unroll
  for (int k = 0; k < 9; k++) s[k] = 0.f;
  for (int ch = 0; ch < 8; ch++) {
    const float* pb = part + ((size_t)(ch * B_ + b) * 9) * DH_ + d;
#pragma unroll
    for (int k = 0; k < 9; k++) s[k] += pb[(size_t)k * DH_];
  }
  int fl = feat_label[d];
#pragma unroll
  for (int k = 0; k < C_; k++) {
    float cntf = fmaxf((float)cnt[k], 1.f);
    float v = (fl == k) ? (s[k] / cntf) : 0.f;
    poolv[((size_t)k * B_ + b) * DH_ + d] = v;
  }
  hg_raw[(size_t)b * DH_ + d] = s[8] * (1.f / NNODE_);
}

// ---------------- tail (parallel split) ----------------

// grid B*C: es[b][key][t] = pl . Wrt[key][:,t] + br[key][t]
__global__ __launch_bounds__(256) void resize_t(const float* __restrict__ poolv,
                                                const float* __restrict__ Wrt,
                                                const float* __restrict__ br,
                                                float* __restrict__ emb) {
  int key = blockIdx.x & 7, b = blockIdx.x >> 3, t = threadIdx.x;
  __shared__ float pl[DH_];
  pl[t] = poolv[((size_t)key * B_ + b) * DH_ + t];
  __syncthreads();
  const float* W = Wrt + (size_t)key * DH_ * DH_;
  float s = 0.f;
  for (int d = 0; d < DH_; d++) s += pl[d] * W[d * DH_ + t];
  emb[((size_t)b * C_ + key) * DH_ + t] = s + br[key * DH_ + t];
}

// grid B*C: q/k/v rows for one (b,c)
__global__ __launch_bounds__(256) void qkv_t(const float* __restrict__ emb,
                                             const float* __restrict__ Wq,
                                             const float* __restrict__ Wk,
                                             const float* __restrict__ Wv,
                                             float* __restrict__ q, float* __restrict__ k,
                                             float* __restrict__ v) {
  int idx = blockIdx.x, t = threadIdx.x;
  __shared__ float x[DH_];
  x[t] = emb[(size_t)idx * DH_ + t];
  __syncthreads();
  float sq = 0.f, sk = 0.f, sv = 0.f;
  for (int kk = 0; kk < DH_; kk++) {
    float xv = x[kk];
    sq += xv * Wq[kk * DH_ + t];
    sk += xv * Wk[kk * DH_ + t];
    sv += xv * Wv[kk * DH_ + t];
  }
  q[(size_t)idx * DH_ + t] = sq;
  k[(size_t)idx * DH_ + t] = sk;
  v[(size_t)idx * DH_ + t] = sv;
}

// grid B: scores + softmax + attn@v -> osb
__global__ __launch_bounds__(256) void attn_core(const float* __restrict__ q,
                                                 const float* __restrict__ k,
                                                 const float* __restrict__ v,
                                                 float* __restrict__ osb) {
  int b = blockIdx.x, t = threadIdx.x;
  __shared__ float qs[C_][DH_], ks[C_][DH_], vs[C_][DH_];
  __shared__ float sc[H_][C_][C_];
  for (int c = 0; c < C_; c++) {
    qs[c][t] = q[((size_t)b * C_ + c) * DH_ + t];
    ks[c][t] = k[((size_t)b * C_ + c) * DH_ + t];
    vs[c][t] = v[((size_t)b * C_ + c) * DH_ + t];
  }
  __syncthreads();
  for (int idx = t; idx < H_ * C_ * C_; idx += 256) {
    int hh = idx / (C_ * C_);
    int qc = (idx / C_) % C_;
    int kc = idx % C_;
    float s = 0.f;
    for (int dd = 0; dd < 32; dd++) s += qs[qc][hh * 32 + dd] * ks[kc][hh * 32 + dd];
    sc[hh][qc][kc] = s * 0.35355339059327373f;
  }
  __syncthreads();
  if (t < H_ * C_) {
    int hh = t / C_, qc = t % C_;
    float m = -1e30f;
    for (int kc = 0; kc < C_; kc++) m = fmaxf(m, sc[hh][qc][kc]);
    float sum = 0.f;
    for (int kc = 0; kc < C_; kc++) { float e = expf(sc[hh][qc][kc] - m); sc[hh][qc][kc] = e; sum += e; }
    float inv = 1.f / sum;
    for (int kc = 0; kc < C_; kc++) sc[hh][qc][kc] *= inv;
  }
  __syncthreads();
  int hh = t >> 5;
  for (int c = 0; c < C_; c++) {
    float s = 0.f;
#pragma unroll
    for (int kc = 0; kc < C_; kc++) s += sc[hh][c][kc] * vs[kc][t];
    osb[((size_t)b * C_ + c) * DH_ + t] = s;
  }
}

// grid B*C: ff = relu(os@lwt + lb) + os + emb
__global__ __launch_bounds__(256) void ff_res(const float* __restrict__ osb,
                                              const float* __restrict__ emb,
                                              const float* __restrict__ lwt,
                                              const float* __restrict__ lb,
                                              float* __restrict__ ffb) {
  int idx = blockIdx.x, t = threadIdx.x;
  __shared__ float ox[DH_];
  ox[t] = osb[(size_t)idx * DH_ + t];
  __syncthreads();
  float s = 0.f;
  for (int d = 0; d < DH_; d++) s += ox[d] * lwt[d * DH_ + t];
  ffb[(size_t)idx * DH_ + t] =
      fmaxf(s + lb[t], 0.f) + ox[t] + emb[(size_t)idx * DH_ + t];
}

// 1 block: ge = mean_c ffb; recon; BN; logits
__global__ __launch_bounds__(256) void tail_final(
    const float* __restrict__ ffb, const float* __restrict__ hg_raw,
    const float* __restrict__ g, const float* __restrict__ be,
    const float* __restrict__ cw, const float* __restrict__ cb,
    float* __restrict__ out) {
  int t = threadIdx.x;
  __shared__ float hgn[B_][DH_];
  __shared__ float red[256];
  float gcol[B_];
  float mu = 0.f;
#pragma unroll
  for (int b = 0; b < B_; b++) {
    float s = 0.f;
    for (int c = 0; c < C_; c++) s += ffb[((size_t)b * C_ + c) * DH_ + t];
    gcol[b] = s * (1.f / C_);
    mu += gcol[b];
  }
  mu *= (1.f / B_);
  float var = 0.f;
#pragma unroll
  for (int b = 0; b < B_; b++) { float x = gcol[b] - mu; var += x * x; }
  var *= (1.f / B_);
  float is = rsqrtf(var + 1e-5f);
  float gm = g[t], bt = be[t];
  float s = 0.f;
#pragma unroll
  for (int b = 0; b < B_; b++) {
    hgn[b][t] = (gcol[b] - mu) * is * gm + bt;
    float d = gcol[b] - hg_raw[b * DH_ + t] + 1e-6f;
    s += d * d;
  }
  red[t] = s;
  __syncthreads();
  for (int w = 128; w > 0; w >>= 1) {
    if (t < w) red[t] += red[t + w];
    __syncthreads();
  }
  if (t == 0) out[B_ * NCLS_] = sqrtf(red[0]);
  for (int o = t; o < B_ * NCLS_; o += 256) {
    int b = o / NCLS_, j = o % NCLS_;
    float sl = cb[j];
    for (int d = 0; d < DH_; d++) sl += hgn[b][d] * cw[j * DH_ + d];
    out[o] = sl;
  }
}

// ---------------- launch ----------------

extern "C" void kernel_launch(void* const* d_in, const int* in_sizes, int n_in,
                              void* d_out, int out_size, void* d_ws, size_t ws_size,
                              hipStream_t stream) {
  const float* h   = (const float*)d_in[0];
  const int* src   = (const int*)d_in[1];
  const int* dst   = (const int*)d_in[2];
  const int* nlab  = (const int*)d_in[3];
  const int* flab  = (const int*)d_in[4];
  const float* W1  = (const float*)d_in[5];
  const float* b1  = (const float*)d_in[6];
  const float* W2  = (const float*)d_in[7];
  const float* b2  = (const float*)d_in[8];
  const float* Wr  = (const float*)d_in[9];
  const float* br  = (const float*)d_in[10];
  const float* Wq  = (const float*)d_in[11];
  const float* Wk  = (const float*)d_in[12];
  const float* Wv  = (const float*)d_in[13];
  const float* lw  = (const float*)d_in[14];
  const float* lb  = (const float*)d_in[15];
  const float* bng = (const float*)d_in[16];
  const float* bnb = (const float*)d_in[17];
  const float* cw  = (const float*)d_in[18];
  const float* cb  = (const float*)d_in[19];
  float* out = (float*)d_out;

  char* p = (char*)d_ws;
  auto alloc = [&](size_t bytes) -> void* {
    void* q = (void*)p;
    p += (bytes + 255) & ~(size_t)255;
    return q;
  };
  unsigned int* xq    = (unsigned int*)alloc((size_t)TOTAL_ * DH_);
  unsigned char* h1q  = (unsigned char*)alloc((size_t)TOTAL_ * DH_);
  unsigned short* h2b = (unsigned short*)alloc((size_t)TOTAL_ * DH_ * 2);
  unsigned short* aggB = (unsigned short*)alloc((size_t)TOTAL_ * 1024 * 2);
  unsigned short* Wt1  = (unsigned short*)alloc((size_t)1024 * DH_ * 2);
  unsigned short* Wt2  = (unsigned short*)alloc((size_t)1024 * DH_ * 2);
  float* Wrt   = (float*)alloc((size_t)C_ * DH_ * DH_ * 4);
  float* lwt   = (float*)alloc((size_t)DH_ * DH_ * 4);
  float* bsum1 = (float*)alloc(DH_ * 4);
  float* bsum2 = (float*)alloc(DH_ * 4);
  int* cnt      = (int*)alloc((size_t)2 * R_ * TOTAL_ * 4);
  float* rs_out = (float*)alloc((size_t)R_ * TOTAL_ * 4);
  float* rs_in  = (float*)alloc((size_t)R_ * TOTAL_ * 4);
  int* csr_off  = (int*)alloc((size_t)R_ * (TOTAL_ + 1) * 4);
  int* csr_pos  = (int*)alloc((size_t)R_ * TOTAL_ * 4);
  int* csr_src  = (int*)alloc((size_t)R_ * E_ * 4);
  float* part   = (float*)alloc((size_t)8 * B_ * 9 * DH_ * 4);
  float* poolv  = (float*)alloc((size_t)C_ * B_ * DH_ * 4);
  float* hg_raw = (float*)alloc((size_t)B_ * DH_ * 4);
  float* emb    = (float*)alloc((size_t)B_ * C_ * DH_ * 4);
  float* qb     = (float*)alloc((size_t)B_ * C_ * DH_ * 4);
  float* kb     = (float*)alloc((size_t)B_ * C_ * DH_ * 4);
  float* vb     = (float*)alloc((size_t)B_ * C_ * DH_ * 4);
  float* osb    = (float*)alloc((size_t)B_ * C_ * DH_ * 4);
  float* ffb    = (float*)alloc((size_t)B_ * C_ * DH_ * 4);

  int* cnt_out = cnt;
  int* cnt_in  = cnt + R_ * TOTAL_;

  // graph prep
  hipMemsetAsync(cnt, 0, (size_t)2 * R_ * TOTAL_ * 4, stream);
  count_deg<<<(R_ * E_ + 255) / 256, 256, 0, stream>>>(src, dst, cnt_out, cnt_in);
  deg_rsqrt<<<(R_ * TOTAL_ + 255) / 256, 256, 0, stream>>>(cnt_out, cnt_in, rs_out, rs_in);
  scan_counts<<<R_, 1024, 0, stream>>>(cnt_in, csr_off, csr_pos);
  build_csr<<<(R_ * E_ + 255) / 256, 256, 0, stream>>>(src, dst, csr_pos, csr_src);

  // weight/bias/input prep
  wconv2<<<2048, 256, 0, stream>>>(W1, W2, Wt1, Wt2);
  bias_sum2<<<2, 256, 0, stream>>>(b1, b2, bsum1, bsum2);
  transpose_mats<<<9 * 256, 256, 0, stream>>>(Wr, lw, Wrt, lwt);
  hconv8<<<TOTAL_ * DH_ / 8 / 256, 256, 0, stream>>>(h, xq);

  // layer 1
  aggregate_f8<<<dim3(TOTAL_ / 8, R_), 256, 0, stream>>>(xq, csr_off, csr_src, rs_out, rs_in, aggB);
  gemm_mfma<0><<<dim3(TOTAL_ / 128, 2), 256, 0, stream>>>(aggB, Wt1, bsum1, h1q, nullptr);

  // layer 2
  aggregate_f8<<<dim3(TOTAL_ / 8, R_), 256, 0, stream>>>((const unsigned int*)h1q, csr_off, csr_src, rs_out, rs_in, aggB);
  gemm_mfma<1><<<dim3(TOTAL_ / 128, 2), 256, 0, stream>>>(aggB, Wt2, bsum2, nullptr, h2b);

  // pooling + tail
  pool_part<<<dim3(B_, 8), 256, 0, stream>>>(h2b, nlab, part);
  pool_fin<<<B_, 256, 0, stream>>>(part, nlab, flab, poolv, hg_raw);
  resize_t<<<B_ * C_, 256, 0, stream>>>(poolv, Wrt, br, emb);
  qkv_t<<<B_ * C_, 256, 0, stream>>>(emb, Wq, Wk, Wv, qb, kb, vb);
  attn_core<<<B_, 256, 0, stream>>>(qb, kb, vb, osb);
  ff_res<<<B_ * C_, 256, 0, stream>>>(osb, emb, lwt, lb, ffb);
  tail_final<<<1, 256, 0, stream>>>(ffb, hg_raw, bng, bnb, cw, cb, out);
}

// Round 5
// 320.675 us; speedup vs baseline: 4.4488x; 1.3741x over previous
//
#include <hip/hip_runtime.h>
#include <math.h>

#define R_ 4
#define TOTAL_ 32768
#define NNODE_ 1024
#define B_ 32
#define DH_ 256
#define C_ 8
#define H_ 8
#define NCLS_ 10
#define E_ 262144
#define S_ 32            // sub-blocks per relation for histogram/scatter
#define CHUNK_ (E_ / S_) // 8192 edges per sub-block

typedef __attribute__((ext_vector_type(8))) short short8v;
typedef __attribute__((ext_vector_type(8))) unsigned short u16x8;
typedef __attribute__((ext_vector_type(4))) float f32x4;
typedef __attribute__((ext_vector_type(2))) float f32x2;
typedef __attribute__((ext_vector_type(2))) unsigned int uint2v;

__device__ inline unsigned short f2bf(float f) {
  unsigned int u = __builtin_bit_cast(unsigned int, f);
  u += 0x7FFF + ((u >> 16) & 1);
  return (unsigned short)(u >> 16);
}
__device__ inline float bf2f(unsigned short s) {
  return __builtin_bit_cast(float, (unsigned int)s << 16);
}

// ---------------- graph prep (atomic-free CSR build) ----------------

// partials layout (u32 words, 2 u16 bins/word):
//   parts[((r*S_ + s)*2 + which)*16384 + w], which: 0=src hist, 1=dst hist
__global__ __launch_bounds__(1024) void hist_part(const int* __restrict__ src,
                                                  const int* __restrict__ dst,
                                                  unsigned int* __restrict__ parts) {
  int r = blockIdx.y, s = blockIdx.x, t = threadIdx.x;
  __shared__ unsigned int hs[16384], hd[16384];
  for (int i = t; i < 16384; i += 1024) { hs[i] = 0; hd[i] = 0; }
  __syncthreads();
  const int* sp = src + (size_t)r * E_ + s * CHUNK_;
  const int* dp = dst + (size_t)r * E_ + s * CHUNK_;
  for (int i = t; i < CHUNK_; i += 1024) {
    int a = sp[i], b = dp[i];
    atomicAdd(&hs[a >> 1], 1u << ((a & 1) * 16));
    atomicAdd(&hd[b >> 1], 1u << ((b & 1) * 16));
  }
  __syncthreads();
  unsigned int* po = parts + ((size_t)(r * S_ + s) * 2) * 16384;
  for (int i = t; i < 16384; i += 1024) { po[i] = hs[i]; po[16384 + i] = hd[i]; }
}

// totals + rsqrt norms (fused deg_rsqrt); one thread = one u32 word (2 nodes)
__global__ void reduce_deg(const unsigned int* __restrict__ parts,
                           float* __restrict__ rs_out, float* __restrict__ rs_in,
                           int* __restrict__ cnt_in) {
  int gid = blockIdx.x * 256 + threadIdx.x;  // 0..65535
  int r = gid >> 14, w = gid & 16383;
  unsigned int s0 = 0, s1 = 0, d0 = 0, d1 = 0;
  for (int s = 0; s < S_; s++) {
    unsigned int ws_ = parts[((size_t)(r * S_ + s) * 2) * 16384 + w];
    unsigned int wd  = parts[((size_t)(r * S_ + s) * 2 + 1) * 16384 + w];
    s0 += ws_ & 0xffff; s1 += ws_ >> 16;
    d0 += wd & 0xffff;  d1 += wd >> 16;
  }
  int n0 = w * 2, n1 = n0 + 1;
  rs_out[r * TOTAL_ + n0] = rsqrtf((float)(s0 + 1));
  rs_out[r * TOTAL_ + n1] = rsqrtf((float)(s1 + 1));
  rs_in[r * TOTAL_ + n0]  = rsqrtf((float)(d0 + 1));
  rs_in[r * TOTAL_ + n1]  = rsqrtf((float)(d1 + 1));
  cnt_in[r * TOTAL_ + n0] = (int)d0;
  cnt_in[r * TOTAL_ + n1] = (int)d1;
}

// one block per relation: exclusive scan of in-degree counts -> CSR offsets
__global__ __launch_bounds__(1024) void scan_counts(const int* __restrict__ cnt_in,
                                                    int* __restrict__ off) {
  int r = blockIdx.x;
  const int* c = cnt_in + r * TOTAL_;
  int* o = off + r * (TOTAL_ + 1);
  __shared__ int part[1024];
  int t = threadIdx.x;
  int base = t * 32;
  int loc[32];
  int s = 0;
#pragma unroll
  for (int j = 0; j < 32; j++) { loc[j] = c[base + j]; s += loc[j]; }
  part[t] = s;
  __syncthreads();
  for (int d = 1; d < 1024; d <<= 1) {
    int v = (t >= d) ? part[t - d] : 0;
    __syncthreads();
    part[t] += v;
    __syncthreads();
  }
  int run = (t == 0) ? 0 : part[t - 1];
#pragma unroll
  for (int j = 0; j < 32; j++) {
    o[base + j] = run;
    run += loc[j];
  }
  if (t == 1023) o[TOTAL_] = run;
}

// per-(r,s,node) base slot = csr_off + prefix of earlier sub-blocks' counts
__global__ void base_gen(const unsigned int* __restrict__ parts,
                         const int* __restrict__ csr_off,
                         unsigned int* __restrict__ sbb) {
  int gid = blockIdx.x * 256 + threadIdx.x;  // 0..65535
  int r = gid >> 14, w = gid & 16383;
  int n0 = w * 2, n1 = n0 + 1;
  unsigned int run0 = (unsigned int)csr_off[r * (TOTAL_ + 1) + n0];
  unsigned int run1 = (unsigned int)csr_off[r * (TOTAL_ + 1) + n1];
  for (int s = 0; s < S_; s++) {
    unsigned int wd = parts[((size_t)(r * S_ + s) * 2 + 1) * 16384 + w];
    sbb[(size_t)(r * S_ + s) * TOTAL_ + n0] = run0;
    sbb[(size_t)(r * S_ + s) * TOTAL_ + n1] = run1;
    run0 += wd & 0xffff;
    run1 += wd >> 16;
  }
}

// scatter edges into CSR using LDS-staged bases (block-local LDS atomics only)
__global__ __launch_bounds__(1024) void scatter_csr(const int* __restrict__ src,
                                                    const int* __restrict__ dst,
                                                    const unsigned int* __restrict__ sbb,
                                                    int* __restrict__ csr_src) {
  int r = blockIdx.y, s = blockIdx.x, t = threadIdx.x;
  __shared__ unsigned int basel[TOTAL_];
  const unsigned int* sb = sbb + (size_t)(r * S_ + s) * TOTAL_;
  for (int i = t; i < TOTAL_; i += 1024) basel[i] = sb[i];
  __syncthreads();
  const int* sp = src + (size_t)r * E_ + s * CHUNK_;
  const int* dp = dst + (size_t)r * E_ + s * CHUNK_;
  int* co = csr_src + (size_t)r * E_;
  for (int i = t; i < CHUNK_; i += 1024) {
    int d = dp[i];
    unsigned int slot = atomicAdd(&basel[d], 1u);
    co[slot] = sp[i];
  }
}

// ---------------- conversions ----------------

__global__ void hconv8(const float* __restrict__ x, unsigned int* __restrict__ xq) {
  size_t i = (size_t)blockIdx.x * blockDim.x + threadIdx.x;
  float4 a = ((const float4*)x)[2 * i];
  float4 b = ((const float4*)x)[2 * i + 1];
  unsigned int lo = 0, hi = 0;
  lo = __builtin_amdgcn_cvt_pk_fp8_f32(a.x, a.y, lo, false);
  lo = __builtin_amdgcn_cvt_pk_fp8_f32(a.z, a.w, lo, true);
  hi = __builtin_amdgcn_cvt_pk_fp8_f32(b.x, b.y, hi, false);
  hi = __builtin_amdgcn_cvt_pk_fp8_f32(b.z, b.w, hi, true);
  uint2v o; o[0] = lo; o[1] = hi;
  *(uint2v*)&xq[2 * i] = o;
}

// stacked W [1024,256] f32 -> Wt [256,1024] bf16, both layers in one launch
__global__ void wconv2(const float* __restrict__ W1, const float* __restrict__ W2,
                       unsigned short* __restrict__ T1, unsigned short* __restrict__ T2) {
  int i = blockIdx.x * blockDim.x + threadIdx.x;  // 0..524287
  const float* W = (i < 262144) ? W1 : W2;
  unsigned short* T = (i < 262144) ? T1 : T2;
  int j = i & 262143;
  int k = j >> 8, c = j & 255;
  T[(size_t)c * 1024 + k] = f2bf(W[j]);
}

__global__ void bias_sum2(const float* __restrict__ b1, const float* __restrict__ b2,
                          float* __restrict__ s1, float* __restrict__ s2) {
  const float* b = blockIdx.x ? b2 : b1;
  float* s = blockIdx.x ? s2 : s1;
  int d = threadIdx.x;
  s[d] = b[d] + b[DH_ + d] + b[2 * DH_ + d] + b[3 * DH_ + d];
}

// transpose Wr (8 mats) + lin_w (1 mat), each 256x256
__global__ void transpose_mats(const float* __restrict__ Wr, const float* __restrict__ lw,
                               float* __restrict__ Wrt, float* __restrict__ lwt) {
  int i = blockIdx.x * blockDim.x + threadIdx.x;  // 9*65536
  int m = i >> 16, j = i & 65535;
  int row = j >> 8, col = j & 255;
  float v = (m < 8) ? Wr[(size_t)m * 65536 + j] : lw[j];
  float* T = (m < 8) ? (Wrt + (size_t)m * 65536) : lwt;
  T[col * 256 + row] = v;
}

// ---------------- aggregation (fp8 gather, 2-way edge unroll) ----------------
__global__ __launch_bounds__(256) void aggregate_f8(
    const unsigned int* __restrict__ xq, const int* __restrict__ csr_off,
    const int* __restrict__ csr_src, const float* __restrict__ rs_out,
    const float* __restrict__ rs_in, unsigned short* __restrict__ aggB) {
  int r = blockIdx.y;
  int node = blockIdx.x * 8 + (threadIdx.x >> 5);
  int lane5 = threadIdx.x & 31;
  const int* offr = csr_off + r * (TOTAL_ + 1);
  const int* srcs = csr_src + (size_t)r * E_;
  const float* rso = rs_out + r * TOTAL_;
  float acc[8];
  {
    uint2v v = *(const uint2v*)&xq[(size_t)node * 64 + lane5 * 2];
    float w = rso[node];
    f32x2 p;
    p = __builtin_amdgcn_cvt_pk_f32_fp8(v[0], false); acc[0] = p[0] * w; acc[1] = p[1] * w;
    p = __builtin_amdgcn_cvt_pk_f32_fp8(v[0], true);  acc[2] = p[0] * w; acc[3] = p[1] * w;
    p = __builtin_amdgcn_cvt_pk_f32_fp8(v[1], false); acc[4] = p[0] * w; acc[5] = p[1] * w;
    p = __builtin_amdgcn_cvt_pk_f32_fp8(v[1], true);  acc[6] = p[0] * w; acc[7] = p[1] * w;
  }
  int e0 = offr[node], e1 = offr[node + 1];
  int e = e0;
  for (; e + 2 <= e1; e += 2) {
    int s0 = srcs[e], s1 = srcs[e + 1];
    uint2v v0 = *(const uint2v*)&xq[(size_t)s0 * 64 + lane5 * 2];
    uint2v v1 = *(const uint2v*)&xq[(size_t)s1 * 64 + lane5 * 2];
    float w0 = rso[s0], w1 = rso[s1];
    f32x2 p;
    p = __builtin_amdgcn_cvt_pk_f32_fp8(v0[0], false); acc[0] += p[0] * w0; acc[1] += p[1] * w0;
    p = __builtin_amdgcn_cvt_pk_f32_fp8(v0[0], true);  acc[2] += p[0] * w0; acc[3] += p[1] * w0;
    p = __builtin_amdgcn_cvt_pk_f32_fp8(v0[1], false); acc[4] += p[0] * w0; acc[5] += p[1] * w0;
    p = __builtin_amdgcn_cvt_pk_f32_fp8(v0[1], true);  acc[6] += p[0] * w0; acc[7] += p[1] * w0;
    p = __builtin_amdgcn_cvt_pk_f32_fp8(v1[0], false); acc[0] += p[0] * w1; acc[1] += p[1] * w1;
    p = __builtin_amdgcn_cvt_pk_f32_fp8(v1[0], true);  acc[2] += p[0] * w1; acc[3] += p[1] * w1;
    p = __builtin_amdgcn_cvt_pk_f32_fp8(v1[1], false); acc[4] += p[0] * w1; acc[5] += p[1] * w1;
    p = __builtin_amdgcn_cvt_pk_f32_fp8(v1[1], true);  acc[6] += p[0] * w1; acc[7] += p[1] * w1;
  }
  if (e < e1) {
    int s0 = srcs[e];
    uint2v v0 = *(const uint2v*)&xq[(size_t)s0 * 64 + lane5 * 2];
    float w0 = rso[s0];
    f32x2 p;
    p = __builtin_amdgcn_cvt_pk_f32_fp8(v0[0], false); acc[0] += p[0] * w0; acc[1] += p[1] * w0;
    p = __builtin_amdgcn_cvt_pk_f32_fp8(v0[0], true);  acc[2] += p[0] * w0; acc[3] += p[1] * w0;
    p = __builtin_amdgcn_cvt_pk_f32_fp8(v0[1], false); acc[4] += p[0] * w0; acc[5] += p[1] * w0;
    p = __builtin_amdgcn_cvt_pk_f32_fp8(v0[1], true);  acc[6] += p[0] * w0; acc[7] += p[1] * w0;
  }
  float wi = rs_in[r * TOTAL_ + node];
  u16x8 o;
#pragma unroll
  for (int j = 0; j < 8; j++) o[j] = f2bf(acc[j] * wi);
  *(u16x8*)&aggB[(size_t)node * 1024 + r * DH_ + lane5 * 8] = o;
}

// ---------------- MFMA GEMM: C[32768,256] = A[32768,1024] @ W ----------------
template <int MODE>
__global__ __launch_bounds__(256) void gemm_mfma(
    const unsigned short* __restrict__ A, const unsigned short* __restrict__ Bt,
    const float* __restrict__ bias, unsigned char* __restrict__ out8,
    unsigned short* __restrict__ out16) {
  __shared__ unsigned short As[128][40];
  __shared__ unsigned short Bs[128][40];
  int t = threadIdx.x;
  int row0 = blockIdx.x * 128, col0 = blockIdx.y * 128;
  int wid = t >> 6, lane = t & 63;
  int wm = wid >> 1, wn = wid & 1;
  int lr = lane & 15, lk = (lane >> 4) * 8;
  f32x4 acc[4][4] = {};
  for (int k0 = 0; k0 < 1024; k0 += 32) {
#pragma unroll
    for (int i = 0; i < 2; i++) {
      int chunk = t + 256 * i;
      int rr = chunk >> 2, kc = (chunk & 3) * 8;
      short8v av = *(const short8v*)&A[(size_t)(row0 + rr) * 1024 + k0 + kc];
      *(short8v*)&As[rr][kc] = av;
      short8v bv = *(const short8v*)&Bt[(size_t)(col0 + rr) * 1024 + k0 + kc];
      *(short8v*)&Bs[rr][kc] = bv;
    }
    __syncthreads();
    short8v afr[4], bfr[4];
#pragma unroll
    for (int m = 0; m < 4; m++) afr[m] = *(const short8v*)&As[wm * 64 + m * 16 + lr][lk];
#pragma unroll
    for (int n = 0; n < 4; n++) bfr[n] = *(const short8v*)&Bs[wn * 64 + n * 16 + lr][lk];
#pragma unroll
    for (int m = 0; m < 4; m++)
#pragma unroll
      for (int n = 0; n < 4; n++)
        acc[m][n] = __builtin_amdgcn_mfma_f32_16x16x32_bf16(afr[m], bfr[n], acc[m][n], 0, 0, 0);
    __syncthreads();
  }
  int lq = lane >> 4;
#pragma unroll
  for (int m = 0; m < 4; m++) {
    int row = row0 + wm * 64 + m * 16 + lq * 4;
#pragma unroll
    for (int n = 0; n < 4; n++) {
      int col = col0 + wn * 64 + n * 16 + lr;
      float bv = bias[col];
#pragma unroll
      for (int q = 0; q < 4; q++) {
        float v = acc[m][n][q] + bv;
        if (MODE == 0) {
          v = fmaxf(v, 0.f);
          int b8 = __builtin_amdgcn_cvt_pk_fp8_f32(v, 0.f, 0, false);
          out8[(size_t)(row + q) * DH_ + col] = (unsigned char)b8;
        } else {
          out16[(size_t)(row + q) * DH_ + col] = f2bf(v);
        }
      }
    }
  }
}

// ---------------- pooling (2-phase, bf16 h2) ----------------

__global__ __launch_bounds__(256) void pool_part(const unsigned short* __restrict__ h2b,
                                                 const int* __restrict__ node_label,
                                                 float* __restrict__ part) {
  int b = blockIdx.x, ch = blockIdx.y, d = threadIdx.x;
  __shared__ int slab[128];
  if (d < 128) slab[d] = node_label[ch * 128 + d];
  __syncthreads();
  float a[C_] = {0.f};
  float at = 0.f;
  const unsigned short* base = h2b + ((size_t)b * NNODE_ + ch * 128) * DH_ + d;
  for (int n = 0; n < 128; n++) {
    float x = bf2f(base[(size_t)n * DH_]);
    int lab = slab[n];
    at += x;
#pragma unroll
    for (int k = 0; k < C_; k++) a[k] += (lab == k) ? x : 0.f;
  }
  float* pb = part + ((size_t)(ch * B_ + b) * 9) * DH_ + d;
#pragma unroll
  for (int k = 0; k < C_; k++) pb[(size_t)k * DH_] = a[k];
  pb[(size_t)8 * DH_] = at;
}

__global__ __launch_bounds__(256) void pool_fin(const float* __restrict__ part,
                                                const int* __restrict__ node_label,
                                                const int* __restrict__ feat_label,
                                                float* __restrict__ poolv,
                                                float* __restrict__ hg_raw) {
  int b = blockIdx.x, d = threadIdx.x;
  __shared__ int cnt[C_];
  if (d < C_) cnt[d] = 0;
  __syncthreads();
  for (int n = d; n < NNODE_; n += 256) atomicAdd(&cnt[node_label[n]], 1);
  __syncthreads();
  float s[9];
#pragma unroll
  for (int k = 0; k < 9; k++) s[k] = 0.f;
  for (int ch = 0; ch < 8; ch++) {
    const float* pb = part + ((size_t)(ch * B_ + b) * 9) * DH_ + d;
#pragma unroll
    for (int k = 0; k < 9; k++) s[k] += pb[(size_t)k * DH_];
  }
  int fl = feat_label[d];
#pragma unroll
  for (int k = 0; k < C_; k++) {
    float cntf = fmaxf((float)cnt[k], 1.f);
    float v = (fl == k) ? (s[k] / cntf) : 0.f;
    poolv[((size_t)k * B_ + b) * DH_ + d] = v;
  }
  hg_raw[(size_t)b * DH_ + d] = s[8] * (1.f / NNODE_);
}

// ---------------- tail (parallel split) ----------------

__global__ __launch_bounds__(256) void resize_t(const float* __restrict__ poolv,
                                                const float* __restrict__ Wrt,
                                                const float* __restrict__ br,
                                                float* __restrict__ emb) {
  int key = blockIdx.x & 7, b = blockIdx.x >> 3, t = threadIdx.x;
  __shared__ float pl[DH_];
  pl[t] = poolv[((size_t)key * B_ + b) * DH_ + t];
  __syncthreads();
  const float* W = Wrt + (size_t)key * DH_ * DH_;
  float s = 0.f;
  for (int d = 0; d < DH_; d++) s += pl[d] * W[d * DH_ + t];
  emb[((size_t)b * C_ + key) * DH_ + t] = s + br[key * DH_ + t];
}

__global__ __launch_bounds__(256) void qkv_t(const float* __restrict__ emb,
                                             const float* __restrict__ Wq,
                                             const float* __restrict__ Wk,
                                             const float* __restrict__ Wv,
                                             float* __restrict__ q, float* __restrict__ k,
                                             float* __restrict__ v) {
  int idx = blockIdx.x, t = threadIdx.x;
  __shared__ float x[DH_];
  x[t] = emb[(size_t)idx * DH_ + t];
  __syncthreads();
  float sq = 0.f, sk = 0.f, sv = 0.f;
  for (int kk = 0; kk < DH_; kk++) {
    float xv = x[kk];
    sq += xv * Wq[kk * DH_ + t];
    sk += xv * Wk[kk * DH_ + t];
    sv += xv * Wv[kk * DH_ + t];
  }
  q[(size_t)idx * DH_ + t] = sq;
  k[(size_t)idx * DH_ + t] = sk;
  v[(size_t)idx * DH_ + t] = sv;
}

__global__ __launch_bounds__(256) void attn_core(const float* __restrict__ q,
                                                 const float* __restrict__ k,
                                                 const float* __restrict__ v,
                                                 float* __restrict__ osb) {
  int b = blockIdx.x, t = threadIdx.x;
  __shared__ float qs[C_][DH_], ks[C_][DH_], vs[C_][DH_];
  __shared__ float sc[H_][C_][C_];
  for (int c = 0; c < C_; c++) {
    qs[c][t] = q[((size_t)b * C_ + c) * DH_ + t];
    ks[c][t] = k[((size_t)b * C_ + c) * DH_ + t];
    vs[c][t] = v[((size_t)b * C_ + c) * DH_ + t];
  }
  __syncthreads();
  for (int idx = t; idx < H_ * C_ * C_; idx += 256) {
    int hh = idx / (C_ * C_);
    int qc = (idx / C_) % C_;
    int kc = idx % C_;
    float s = 0.f;
    for (int dd = 0; dd < 32; dd++) s += qs[qc][hh * 32 + dd] * ks[kc][hh * 32 + dd];
    sc[hh][qc][kc] = s * 0.35355339059327373f;
  }
  __syncthreads();
  if (t < H_ * C_) {
    int hh = t / C_, qc = t % C_;
    float m = -1e30f;
    for (int kc = 0; kc < C_; kc++) m = fmaxf(m, sc[hh][qc][kc]);
    float sum = 0.f;
    for (int kc = 0; kc < C_; kc++) { float e = expf(sc[hh][qc][kc] - m); sc[hh][qc][kc] = e; sum += e; }
    float inv = 1.f / sum;
    for (int kc = 0; kc < C_; kc++) sc[hh][qc][kc] *= inv;
  }
  __syncthreads();
  int hh = t >> 5;
  for (int c = 0; c < C_; c++) {
    float s = 0.f;
#pragma unroll
    for (int kc = 0; kc < C_; kc++) s += sc[hh][c][kc] * vs[kc][t];
    osb[((size_t)b * C_ + c) * DH_ + t] = s;
  }
}

__global__ __launch_bounds__(256) void ff_res(const float* __restrict__ osb,
                                              const float* __restrict__ emb,
                                              const float* __restrict__ lwt,
                                              const float* __restrict__ lb,
                                              float* __restrict__ ffb) {
  int idx = blockIdx.x, t = threadIdx.x;
  __shared__ float ox[DH_];
  ox[t] = osb[(size_t)idx * DH_ + t];
  __syncthreads();
  float s = 0.f;
  for (int d = 0; d < DH_; d++) s += ox[d] * lwt[d * DH_ + t];
  ffb[(size_t)idx * DH_ + t] =
      fmaxf(s + lb[t], 0.f) + ox[t] + emb[(size_t)idx * DH_ + t];
}

__global__ __launch_bounds__(256) void tail_final(
    const float* __restrict__ ffb, const float* __restrict__ hg_raw,
    const float* __restrict__ g, const float* __restrict__ be,
    const float* __restrict__ cw, const float* __restrict__ cb,
    float* __restrict__ out) {
  int t = threadIdx.x;
  __shared__ float hgn[B_][DH_];
  __shared__ float red[256];
  float gcol[B_];
  float mu = 0.f;
#pragma unroll
  for (int b = 0; b < B_; b++) {
    float s = 0.f;
    for (int c = 0; c < C_; c++) s += ffb[((size_t)b * C_ + c) * DH_ + t];
    gcol[b] = s * (1.f / C_);
    mu += gcol[b];
  }
  mu *= (1.f / B_);
  float var = 0.f;
#pragma unroll
  for (int b = 0; b < B_; b++) { float x = gcol[b] - mu; var += x * x; }
  var *= (1.f / B_);
  float is = rsqrtf(var + 1e-5f);
  float gm = g[t], bt = be[t];
  float s = 0.f;
#pragma unroll
  for (int b = 0; b < B_; b++) {
    hgn[b][t] = (gcol[b] - mu) * is * gm + bt;
    float d = gcol[b] - hg_raw[b * DH_ + t] + 1e-6f;
    s += d * d;
  }
  red[t] = s;
  __syncthreads();
  for (int w = 128; w > 0; w >>= 1) {
    if (t < w) red[t] += red[t + w];
    __syncthreads();
  }
  if (t == 0) out[B_ * NCLS_] = sqrtf(red[0]);
  for (int o = t; o < B_ * NCLS_; o += 256) {
    int b = o / NCLS_, j = o % NCLS_;
    float sl = cb[j];
    for (int d = 0; d < DH_; d++) sl += hgn[b][d] * cw[j * DH_ + d];
    out[o] = sl;
  }
}

// ---------------- launch ----------------

extern "C" void kernel_launch(void* const* d_in, const int* in_sizes, int n_in,
                              void* d_out, int out_size, void* d_ws, size_t ws_size,
                              hipStream_t stream) {
  const float* h   = (const float*)d_in[0];
  const int* src   = (const int*)d_in[1];
  const int* dst   = (const int*)d_in[2];
  const int* nlab  = (const int*)d_in[3];
  const int* flab  = (const int*)d_in[4];
  const float* W1  = (const float*)d_in[5];
  const float* b1  = (const float*)d_in[6];
  const float* W2  = (const float*)d_in[7];
  const float* b2  = (const float*)d_in[8];
  const float* Wr  = (const float*)d_in[9];
  const float* br  = (const float*)d_in[10];
  const float* Wq  = (const float*)d_in[11];
  const float* Wk  = (const float*)d_in[12];
  const float* Wv  = (const float*)d_in[13];
  const float* lw  = (const float*)d_in[14];
  const float* lb  = (const float*)d_in[15];
  const float* bng = (const float*)d_in[16];
  const float* bnb = (const float*)d_in[17];
  const float* cw  = (const float*)d_in[18];
  const float* cb  = (const float*)d_in[19];
  float* out = (float*)d_out;

  char* p = (char*)d_ws;
  auto alloc = [&](size_t bytes) -> void* {
    void* q = (void*)p;
    p += (bytes + 255) & ~(size_t)255;
    return q;
  };
  unsigned int* xq    = (unsigned int*)alloc((size_t)TOTAL_ * DH_);
  unsigned char* h1q  = (unsigned char*)alloc((size_t)TOTAL_ * DH_);
  unsigned short* h2b = (unsigned short*)alloc((size_t)TOTAL_ * DH_ * 2);
  unsigned short* aggB = (unsigned short*)alloc((size_t)TOTAL_ * 1024 * 2);  // 64MB
  unsigned short* Wt1  = (unsigned short*)alloc((size_t)1024 * DH_ * 2);
  unsigned short* Wt2  = (unsigned short*)alloc((size_t)1024 * DH_ * 2);
  float* Wrt   = (float*)alloc((size_t)C_ * DH_ * DH_ * 4);
  float* lwt   = (float*)alloc((size_t)DH_ * DH_ * 4);
  float* bsum1 = (float*)alloc(DH_ * 4);
  float* bsum2 = (float*)alloc(DH_ * 4);
  int* cnt_in   = (int*)alloc((size_t)R_ * TOTAL_ * 4);
  float* rs_out = (float*)alloc((size_t)R_ * TOTAL_ * 4);
  float* rs_in  = (float*)alloc((size_t)R_ * TOTAL_ * 4);
  int* csr_off  = (int*)alloc((size_t)R_ * (TOTAL_ + 1) * 4);
  int* csr_src  = (int*)alloc((size_t)R_ * E_ * 4);
  float* part   = (float*)alloc((size_t)8 * B_ * 9 * DH_ * 4);
  float* poolv  = (float*)alloc((size_t)C_ * B_ * DH_ * 4);
  float* hg_raw = (float*)alloc((size_t)B_ * DH_ * 4);
  float* emb    = (float*)alloc((size_t)B_ * C_ * DH_ * 4);
  float* qb     = (float*)alloc((size_t)B_ * C_ * DH_ * 4);
  float* kb     = (float*)alloc((size_t)B_ * C_ * DH_ * 4);
  float* vb     = (float*)alloc((size_t)B_ * C_ * DH_ * 4);
  float* osb    = (float*)alloc((size_t)B_ * C_ * DH_ * 4);
  float* ffb    = (float*)alloc((size_t)B_ * C_ * DH_ * 4);

  // prep-phase scratch aliased onto aggB (dead until aggregation; same-stream
  // serialization guarantees prep completes before aggregate_f8 writes aggB)
  unsigned int* parts = (unsigned int*)aggB;                        // 16MB
  unsigned int* sbb   = (unsigned int*)((char*)aggB + (size_t)16 * 1024 * 1024);  // 16MB

  // graph prep (no global atomics)
  hist_part<<<dim3(S_, R_), 1024, 0, stream>>>(src, dst, parts);
  reduce_deg<<<R_ * TOTAL_ / 512, 256, 0, stream>>>(parts, rs_out, rs_in, cnt_in);
  scan_counts<<<R_, 1024, 0, stream>>>(cnt_in, csr_off);
  base_gen<<<R_ * TOTAL_ / 512, 256, 0, stream>>>(parts, csr_off, sbb);
  scatter_csr<<<dim3(S_, R_), 1024, 0, stream>>>(src, dst, sbb, csr_src);

  // weight/bias/input prep
  wconv2<<<2048, 256, 0, stream>>>(W1, W2, Wt1, Wt2);
  bias_sum2<<<2, 256, 0, stream>>>(b1, b2, bsum1, bsum2);
  transpose_mats<<<9 * 256, 256, 0, stream>>>(Wr, lw, Wrt, lwt);
  hconv8<<<TOTAL_ * DH_ / 8 / 256, 256, 0, stream>>>(h, xq);

  // layer 1
  aggregate_f8<<<dim3(TOTAL_ / 8, R_), 256, 0, stream>>>(xq, csr_off, csr_src, rs_out, rs_in, aggB);
  gemm_mfma<0><<<dim3(TOTAL_ / 128, 2), 256, 0, stream>>>(aggB, Wt1, bsum1, h1q, nullptr);

  // layer 2
  aggregate_f8<<<dim3(TOTAL_ / 8, R_), 256, 0, stream>>>((const unsigned int*)h1q, csr_off, csr_src, rs_out, rs_in, aggB);
  gemm_mfma<1><<<dim3(TOTAL_ / 128, 2), 256, 0, stream>>>(aggB, Wt2, bsum2, nullptr, h2b);

  // pooling + tail
  pool_part<<<dim3(B_, 8), 256, 0, stream>>>(h2b, nlab, part);
  pool_fin<<<B_, 256, 0, stream>>>(part, nlab, flab, poolv, hg_raw);
  resize_t<<<B_ * C_, 256, 0, stream>>>(poolv, Wrt, br, emb);
  qkv_t<<<B_ * C_, 256, 0, stream>>>(emb, Wq, Wk, Wv, qb, kb, vb);
  attn_core<<<B_, 256, 0, stream>>>(qb, kb, vb, osb);
  ff_res<<<B_ * C_, 256, 0, stream>>>(osb, emb, lwt, lb, ffb);
  tail_final<<<1, 256, 0, stream>>>(ffb, hg_raw, bng, bnb, cw, cb, out);
}